// Round 9
// baseline (1261.356 us; speedup 1.0000x reference)
//
#include <hip/hip_runtime.h>
#include <hip/hip_bf16.h>
#include <hip/hip_fp16.h>
#include <math.h>

// Problem constants (from reference)
#define N_NODES 50000
#define N_EDGES 800000
#define N_TOT   (N_EDGES + N_NODES)  // 850000 edges incl. self loops
#define NEG_SLOPE 0.2f

static __device__ __forceinline__ float lrelu(float x){ return x >= 0.f ? x : NEG_SLOPE * x; }

// ---------------- CSR build ----------------
// k_init: deg=1 (self loop) + fused int64/int32 edge-dtype detect (lane 0).
__global__ void k_init(const int* __restrict__ ei, int* __restrict__ flag,
                       int* __restrict__ deg){
  int i = blockIdx.x * blockDim.x + threadIdx.x;
  if (i == 0){
    int o = 0;
    #pragma unroll
    for (int j = 1; j < 16; j += 2) o |= ei[j];
    *flag = (o == 0) ? 1 : 0;  // 1 => int64 layout
  }
  if (i < N_NODES) deg[i] = 1;
}

// 2 edges per thread, vectorized dst reads.
__global__ void k_count(const int* __restrict__ ei, const int* __restrict__ flag,
                        int* __restrict__ deg){
  int t = blockIdx.x * blockDim.x + threadIdx.x;
  if (t >= N_EDGES / 2) return;
  int d0, d1;
  if (*flag){
    int4 dv = *(const int4*)&ei[2 * N_EDGES + 4 * t];
    d0 = dv.x; d1 = dv.z;
  } else {
    int2 dv = *(const int2*)&ei[N_EDGES + 2 * t];
    d0 = dv.x; d1 = dv.y;
  }
  atomicAdd(&deg[d0], 1);
  atomicAdd(&deg[d1], 1);
}

// block-scan: 49 blocks x 1024 elements (256 thr x 4)
__global__ void k_scan1(const int* __restrict__ deg, int* __restrict__ rowptr,
                        int* __restrict__ bsum){
  __shared__ int sd[256];
  int t = threadIdx.x;
  int base = blockIdx.x * 1024 + t * 4;
  int v0 = (base + 0 < N_NODES) ? deg[base + 0] : 0;
  int v1 = (base + 1 < N_NODES) ? deg[base + 1] : 0;
  int v2 = (base + 2 < N_NODES) ? deg[base + 2] : 0;
  int v3 = (base + 3 < N_NODES) ? deg[base + 3] : 0;
  int tsum = v0 + v1 + v2 + v3;
  sd[t] = tsum; __syncthreads();
  for (int off = 1; off < 256; off <<= 1){
    int vv = (t >= off) ? sd[t - off] : 0;
    __syncthreads();
    sd[t] += vv;
    __syncthreads();
  }
  int excl = sd[t] - tsum;
  if (base + 0 < N_NODES) rowptr[base + 0] = excl;
  if (base + 1 < N_NODES) rowptr[base + 1] = excl + v0;
  if (base + 2 < N_NODES) rowptr[base + 2] = excl + v0 + v1;
  if (base + 3 < N_NODES) rowptr[base + 3] = excl + v0 + v1 + v2;
  if (t == 255) bsum[blockIdx.x] = sd[255];
}

#define NB_SCAN 49
__global__ void k_scan2(const int* __restrict__ bsum, int* __restrict__ boff){
  int t = threadIdx.x;  // 64 threads, 1 block
  int v = (t < NB_SCAN) ? bsum[t] : 0;
  int incl = v;
  #pragma unroll
  for (int off = 1; off < 64; off <<= 1){
    int u = __shfl_up(incl, off);
    if (t >= off) incl += u;
  }
  if (t < NB_SCAN) boff[t] = incl - v;
}

// writes fill = rowptr so scatter needs no rowptr read (atomicAdd returns slot)
__global__ void k_scan3(int* __restrict__ rowptr, const int* __restrict__ boff,
                        int* __restrict__ fill){
  int i = blockIdx.x * blockDim.x + threadIdx.x;
  if (i < N_NODES){
    int v = rowptr[i] + boff[i >> 10];
    rowptr[i] = v;
    fill[i] = v;
  }
  if (i == 0) rowptr[N_NODES] = N_TOT;
}

// 2 edges per thread (vectorized src+dst reads); tail threads place self loops.
__global__ void k_scatter(const int* __restrict__ ei, const int* __restrict__ flag,
                          int* __restrict__ fill, int* __restrict__ col){
  int t = blockIdx.x * blockDim.x + threadIdx.x;
  if (t < N_EDGES / 2){
    int s0, s1, d0, d1;
    if (*flag){
      int4 sv = *(const int4*)&ei[4 * t];
      int4 dv = *(const int4*)&ei[2 * N_EDGES + 4 * t];
      s0 = sv.x; s1 = sv.z; d0 = dv.x; d1 = dv.z;
    } else {
      int2 sv = *(const int2*)&ei[2 * t];
      int2 dv = *(const int2*)&ei[N_EDGES + 2 * t];
      s0 = sv.x; s1 = sv.y; d0 = dv.x; d1 = dv.y;
    }
    col[atomicAdd(&fill[d0], 1)] = s0;
    col[atomicAdd(&fill[d1], 1)] = s1;
  } else {
    int n = t - N_EDGES / 2;
    if (n < N_NODES) col[atomicAdd(&fill[n], 1)] = n;   // self loop
  }
}

// ---------------- feature transforms ----------------
// h is stored as fp16 (halves gather bytes in k_agg); es/ed computed from the
// unrounded f32 accumulators so attention coefficients stay near-exact.

// layer 1: x[N,8] @ W[8,256] -> h[N,256] (fp16); e_src/e_dst[N,4] (f32)
__global__ __launch_bounds__(256) void k_transform1(
    const float* __restrict__ xin, const float* __restrict__ W,
    const float* __restrict__ aS, const float* __restrict__ aD,
    __half* __restrict__ h, float* __restrict__ es, float* __restrict__ ed){
  __shared__ float wl[8 * 256];
  int tid = threadIdx.x;
  for (int i = tid; i < 8 * 256; i += 256) wl[i] = W[i];
  int lane = tid & 63, wv = tid >> 6, head = lane >> 4;
  float4 s4 = *(const float4*)&aS[4 * lane];
  float4 d4 = *(const float4*)&aD[4 * lane];
  __syncthreads();
  int base = (blockIdx.x * 4 + wv) * 8;   // 8 nodes per wave
  for (int m = 0; m < 8; m++){
    int n = base + m;
    if (n >= N_NODES) break;
    float4 xa = *(const float4*)&xin[n * 8];
    float4 xb = *(const float4*)&xin[n * 8 + 4];
    float xs0 = xa.x, xs1 = xa.y, xs2 = xa.z, xs3 = xa.w;
    float xs4 = xb.x, xs5 = xb.y, xs6 = xb.z, xs7 = xb.w;
    float4 acc = make_float4(0.f, 0.f, 0.f, 0.f);
    #define T1STEP(k, xv) { float4 w4 = *(const float4*)&wl[(k)*256 + 4*lane]; \
      acc.x = fmaf(xv, w4.x, acc.x); acc.y = fmaf(xv, w4.y, acc.y); \
      acc.z = fmaf(xv, w4.z, acc.z); acc.w = fmaf(xv, w4.w, acc.w); }
    T1STEP(0, xs0) T1STEP(1, xs1) T1STEP(2, xs2) T1STEP(3, xs3)
    T1STEP(4, xs4) T1STEP(5, xs5) T1STEP(6, xs6) T1STEP(7, xs7)
    #undef T1STEP
    __half2 p0 = __floats2half2_rn(acc.x, acc.y);
    __half2 p1 = __floats2half2_rn(acc.z, acc.w);
    uint2 u; u.x = *(unsigned int*)&p0; u.y = *(unsigned int*)&p1;
    *(uint2*)&h[(size_t)n * 256 + 4 * lane] = u;
    float ps = acc.x*s4.x + acc.y*s4.y + acc.z*s4.z + acc.w*s4.w;
    float pd = acc.x*d4.x + acc.y*d4.y + acc.z*d4.z + acc.w*d4.w;
    #pragma unroll
    for (int off = 1; off < 16; off <<= 1){ ps += __shfl_xor(ps, off); pd += __shfl_xor(pd, off); }
    if ((lane & 15) == 0){ es[n * 4 + head] = ps; ed[n * 4 + head] = pd; }
  }
}

// layer 2: feat[N,64] @ W[64,256] -> h[N,256] (fp16); e_src/e_dst[N,4]
// Two-stage K over a 32 KiB LDS tile; inner k fully unrolled so the
// __shfl broadcast lane is a compile-time immediate (v_readlane).
__global__ __launch_bounds__(256) void k_transform2(
    const float* __restrict__ xin, const float* __restrict__ W,
    const float* __restrict__ aS, const float* __restrict__ aD,
    __half* __restrict__ h, float* __restrict__ es, float* __restrict__ ed){
  __shared__ float wl[32 * 256];   // 32 KiB
  int tid = threadIdx.x;
  int lane = tid & 63, wv = tid >> 6, head = lane >> 4;
  float4 s4 = *(const float4*)&aS[4 * lane];
  float4 d4 = *(const float4*)&aD[4 * lane];
  int base = (blockIdx.x * 4 + wv) * 8;   // 8 nodes per wave
  float xr[8];
  #pragma unroll
  for (int m = 0; m < 8; m++){
    int n = base + m;
    xr[m] = (n < N_NODES) ? xin[(size_t)n * 64 + lane] : 0.f;
  }
  float4 acc[8];
  #pragma unroll
  for (int m = 0; m < 8; m++) acc[m] = make_float4(0.f, 0.f, 0.f, 0.f);
  #pragma unroll
  for (int hf = 0; hf < 2; hf++){
    if (hf) __syncthreads();   // all reads of previous half done
    const float4* Wv = (const float4*)(W + hf * 32 * 256);
    float4* wlv = (float4*)wl;
    #pragma unroll
    for (int i = 0; i < 8; i++) wlv[tid + 256 * i] = Wv[tid + 256 * i];
    __syncthreads();
    #pragma unroll
    for (int k = 0; k < 32; k++){
      float4 w4 = *(const float4*)&wl[k * 256 + 4 * lane];
      #pragma unroll
      for (int m = 0; m < 8; m++){
        float xv = __shfl(xr[m], hf * 32 + k);
        acc[m].x = fmaf(xv, w4.x, acc[m].x);
        acc[m].y = fmaf(xv, w4.y, acc[m].y);
        acc[m].z = fmaf(xv, w4.z, acc[m].z);
        acc[m].w = fmaf(xv, w4.w, acc[m].w);
      }
    }
  }
  #pragma unroll
  for (int m = 0; m < 8; m++){
    int n = base + m;
    if (n >= N_NODES) break;
    __half2 p0 = __floats2half2_rn(acc[m].x, acc[m].y);
    __half2 p1 = __floats2half2_rn(acc[m].z, acc[m].w);
    uint2 u; u.x = *(unsigned int*)&p0; u.y = *(unsigned int*)&p1;
    *(uint2*)&h[(size_t)n * 256 + 4 * lane] = u;
    float ps = acc[m].x*s4.x + acc[m].y*s4.y + acc[m].z*s4.z + acc[m].w*s4.w;
    float pd = acc[m].x*d4.x + acc[m].y*d4.y + acc[m].z*d4.z + acc[m].w*d4.w;
    #pragma unroll
    for (int off = 1; off < 16; off <<= 1){ ps += __shfl_xor(ps, off); pd += __shfl_xor(pd, off); }
    if ((lane & 15) == 0){ es[n * 4 + head] = ps; ed[n * 4 + head] = pd; }
  }
}

// layer 3: feat[N,64] @ W3[64,1] -> pk[N]={es3,h3} (packed), ed3[N]
__global__ __launch_bounds__(256) void k_transform3(
    const float* __restrict__ xin, const float* __restrict__ W3,
    const float* __restrict__ aS, const float* __restrict__ aD,
    float2* __restrict__ pk, float* __restrict__ ed3){
  int gid = blockIdx.x * blockDim.x + threadIdx.x;
  int n = gid >> 6, lane = gid & 63;
  if (n >= N_NODES) return;
  float v = xin[(size_t)n * 64 + lane] * W3[lane];
  #pragma unroll
  for (int off = 1; off < 64; off <<= 1) v += __shfl_xor(v, off);
  if (lane == 0){
    pk[n] = make_float2(v * aS[0], v);   // (es3, h3) one 8B gather in agg3
    ed3[n] = v * aD[0];
  }
}

// ---------------- aggregation (layers 1,2): one wave per dst node ----------------
// No-max softmax (logits O(1-5) analytically; shift-invariant => identical math).
// 8-way unroll: 8 independent 1KB h-gathers + 8 es loads in flight per wave
// (latency-limited regime probe; R7 showed BW tracks requests-in-flight).
static __device__ __forceinline__ void agg_step(float4& acc, uint2 u, float wt){
  float2 aa = __half22float2(*(__half2*)&u.x);
  float2 bb = __half22float2(*(__half2*)&u.y);
  acc.x = fmaf(wt, aa.x, acc.x); acc.y = fmaf(wt, aa.y, acc.y);
  acc.z = fmaf(wt, bb.x, acc.z); acc.w = fmaf(wt, bb.y, acc.w);
}

__global__ __launch_bounds__(256) void k_agg(
    const __half* __restrict__ h, const float* __restrict__ es, const float* __restrict__ ed,
    const int* __restrict__ rowptr, const int* __restrict__ col,
    const float* __restrict__ bias, float* __restrict__ outf){
  int gid = blockIdx.x * blockDim.x + threadIdx.x;
  int d = gid >> 6, lane = gid & 63;
  if (d >= N_NODES) return;
  int start = rowptr[d], end = rowptr[d + 1];
  int head = lane >> 4;
  float eh = ed[d * 4 + head];          // 4 distinct addrs per wave, L2-hot
  const __half* hp = h + 4 * lane;
  float4 acc = make_float4(0.f, 0.f, 0.f, 0.f);
  float wsum = 0.f;
  int i = start;
  for (; i + 8 <= end; i += 8){
    int s0 = col[i],     s1 = col[i + 1], s2 = col[i + 2], s3 = col[i + 3];
    int s4 = col[i + 4], s5 = col[i + 5], s6 = col[i + 6], s7 = col[i + 7];
    uint2 u0 = *(const uint2*)(hp + (size_t)s0 * 256);
    uint2 u1 = *(const uint2*)(hp + (size_t)s1 * 256);
    uint2 u2 = *(const uint2*)(hp + (size_t)s2 * 256);
    uint2 u3 = *(const uint2*)(hp + (size_t)s3 * 256);
    uint2 u4 = *(const uint2*)(hp + (size_t)s4 * 256);
    uint2 u5 = *(const uint2*)(hp + (size_t)s5 * 256);
    uint2 u6 = *(const uint2*)(hp + (size_t)s6 * 256);
    uint2 u7 = *(const uint2*)(hp + (size_t)s7 * 256);
    float e0 = es[s0 * 4 + head], e1 = es[s1 * 4 + head];
    float e2 = es[s2 * 4 + head], e3 = es[s3 * 4 + head];
    float e4 = es[s4 * 4 + head], e5 = es[s5 * 4 + head];
    float e6 = es[s6 * 4 + head], e7 = es[s7 * 4 + head];
    float w0 = __expf(lrelu(e0 + eh)), w1 = __expf(lrelu(e1 + eh));
    float w2 = __expf(lrelu(e2 + eh)), w3 = __expf(lrelu(e3 + eh));
    float w4 = __expf(lrelu(e4 + eh)), w5 = __expf(lrelu(e5 + eh));
    float w6 = __expf(lrelu(e6 + eh)), w7 = __expf(lrelu(e7 + eh));
    wsum += ((w0 + w1) + (w2 + w3)) + ((w4 + w5) + (w6 + w7));
    agg_step(acc, u0, w0); agg_step(acc, u1, w1);
    agg_step(acc, u2, w2); agg_step(acc, u3, w3);
    agg_step(acc, u4, w4); agg_step(acc, u5, w5);
    agg_step(acc, u6, w6); agg_step(acc, u7, w7);
  }
  for (; i < end; i++){
    int s0 = col[i];
    uint2 u0 = *(const uint2*)(hp + (size_t)s0 * 256);
    float w0 = __expf(lrelu(es[s0 * 4 + head] + eh));
    wsum += w0;
    agg_step(acc, u0, w0);
  }
  float inv = 1.0f / (wsum + 1e-16f);
  acc.x *= inv; acc.y *= inv; acc.z *= inv; acc.w *= inv;
  // mean over heads: sum lanes differing in bits 4,5
  #pragma unroll
  for (int off = 16; off < 64; off <<= 1){
    acc.x += __shfl_xor(acc.x, off);
    acc.y += __shfl_xor(acc.y, off);
    acc.z += __shfl_xor(acc.z, off);
    acc.w += __shfl_xor(acc.w, off);
  }
  if (lane < 16){
    float4 b4 = *(const float4*)&bias[4 * lane];
    float ox = 0.25f * acc.x + b4.x;
    float oy = 0.25f * acc.y + b4.y;
    float oz = 0.25f * acc.z + b4.z;
    float ow = 0.25f * acc.w + b4.w;
    ox = ox > 0.f ? ox : expm1f(ox);   // ELU
    oy = oy > 0.f ? oy : expm1f(oy);
    oz = oz > 0.f ? oz : expm1f(oz);
    ow = ow > 0.f ? ow : expm1f(ow);
    float4 o = make_float4(ox, oy, oz, ow);
    *(float4*)&outf[(size_t)d * 64 + 4 * lane] = o;
  }
}

// ---------------- aggregation layer 3 (1 head, 1 channel) + sigmoid ----------------
// 4 nodes per wave, 16 lanes each; packed (es3,h3) => one 8B gather per edge.
__global__ __launch_bounds__(256) void k_agg3(
    const float2* __restrict__ pk, const float* __restrict__ ed3,
    const int* __restrict__ rowptr, const int* __restrict__ col,
    const float* __restrict__ b3, float* __restrict__ out){
  int gid = blockIdx.x * blockDim.x + threadIdx.x;
  int wv = gid >> 6, lane = gid & 63;
  int sub = lane >> 4, li = lane & 15;
  int d = wv * 4 + sub;
  if (d < N_NODES){
    int start = rowptr[d], end = rowptr[d + 1];
    float edv = ed3[d];
    float num = 0.f, den = 0.f;
    for (int i = start + li; i < end; i += 16){
      float2 p = pk[col[i]];
      float wgt = __expf(lrelu(p.x + edv));   // no-max softmax
      den += wgt;
      num = fmaf(wgt, p.y, num);
    }
    #pragma unroll
    for (int off = 1; off < 16; off <<= 1){
      num += __shfl_xor(num, off);
      den += __shfl_xor(den, off);
    }
    if (li == 0){
      float v = num / (den + 1e-16f) + b3[0];
      out[d] = 1.f / (1.f + __expf(-v));
    }
  }
}

// ---------------- launcher ----------------
extern "C" void kernel_launch(void* const* d_in, const int* in_sizes, int n_in,
                              void* d_out, int out_size, void* d_ws, size_t ws_size,
                              hipStream_t stream) {
  const float* x   = (const float*)d_in[0];
  const int*   ei  = (const int*)  d_in[1];
  const float* W1  = (const float*)d_in[2];
  const float* b1  = (const float*)d_in[3];
  const float* as1 = (const float*)d_in[4];
  const float* ad1 = (const float*)d_in[5];
  const float* W2  = (const float*)d_in[6];
  const float* b2  = (const float*)d_in[7];
  const float* as2 = (const float*)d_in[8];
  const float* ad2 = (const float*)d_in[9];
  const float* W3  = (const float*)d_in[10];
  const float* b3  = (const float*)d_in[11];
  const float* as3 = (const float*)d_in[12];
  const float* ad3 = (const float*)d_in[13];
  float* out = (float*)d_out;

  // workspace layout (all offsets 256B-aligned)
  char* w = (char*)d_ws;
  size_t off = 0;
  auto alloc = [&](size_t bytes) -> char* {
    char* p = w + off;
    off += (bytes + 255) & ~size_t(255);
    return p;
  };
  int*    flag   = (int*)   alloc(64);
  int*    deg    = (int*)   alloc(N_NODES * 4);
  int*    fill   = (int*)   alloc(N_NODES * 4);
  int*    rowptr = (int*)   alloc((N_NODES + 1) * 4);
  int*    bsum   = (int*)   alloc(64 * 4);
  int*    boff   = (int*)   alloc(64 * 4);
  int*    col    = (int*)   alloc((size_t)N_TOT * 4);
  __half* h      = (__half*)alloc((size_t)N_NODES * 256 * 2);  // 25.6 MB fp16
  float*  es     = (float*) alloc((size_t)N_NODES * 4 * 4);
  float*  ed     = (float*) alloc((size_t)N_NODES * 4 * 4);
  float*  feat1  = (float*) alloc((size_t)N_NODES * 64 * 4);   // 12.8 MB
  float*  feat2  = (float*) alloc((size_t)N_NODES * 64 * 4);   // 12.8 MB
  float2* pk     = (float2*)alloc((size_t)N_NODES * 8);
  float*  ed3    = (float*) alloc(N_NODES * 4);
  (void)ws_size; (void)in_sizes; (void)n_in; (void)out_size;

  // ---- CSR build (shared by all 3 layers) ----
  k_init   <<<(N_NODES + 255) / 256, 256, 0, stream>>>(ei, flag, deg);
  k_count  <<<(N_EDGES / 2 + 255) / 256, 256, 0, stream>>>(ei, flag, deg);
  k_scan1  <<<NB_SCAN, 256, 0, stream>>>(deg, rowptr, bsum);
  k_scan2  <<<1, 64, 0, stream>>>(bsum, boff);
  k_scan3  <<<(N_NODES + 255) / 256, 256, 0, stream>>>(rowptr, boff, fill);
  k_scatter<<<(N_EDGES / 2 + N_NODES + 255) / 256, 256, 0, stream>>>(ei, flag, fill, col);

  const int grid_t12 = (N_NODES + 31) / 32;        // 8 nodes/wave * 4 waves
  const int grid_wpn = (N_NODES * 64 + 255) / 256; // wave per node
  const int grid_w4n = ((N_NODES + 3) / 4 * 64 + 255) / 256; // 4 nodes per wave

  // ---- layer 1 ----
  k_transform1<<<grid_t12, 256, 0, stream>>>(x, W1, as1, ad1, h, es, ed);
  k_agg       <<<grid_wpn, 256, 0, stream>>>(h, es, ed, rowptr, col, b1, feat1);
  // ---- layer 2 ----
  k_transform2<<<grid_t12, 256, 0, stream>>>(feat1, W2, as2, ad2, h, es, ed);
  k_agg       <<<grid_wpn, 256, 0, stream>>>(h, es, ed, rowptr, col, b2, feat2);
  // ---- layer 3 ----
  k_transform3<<<grid_wpn, 256, 0, stream>>>(feat2, W3, as3, ad3, pk, ed3);
  k_agg3      <<<grid_w4n, 256, 0, stream>>>(pk, ed3, rowptr, col, b3, out);
}

// Round 11
// 408.701 us; speedup vs baseline: 3.0863x; 3.0863x over previous
//
#include <hip/hip_runtime.h>
#include <hip/hip_bf16.h>
#include <hip/hip_fp16.h>
#include <math.h>

// Problem constants (from reference)
#define N_NODES 50000
#define N_EDGES 800000
#define N_TOT   (N_EDGES + N_NODES)  // 850000 edges incl. self loops
#define NEG_SLOPE 0.2f

static __device__ __forceinline__ float lrelu(float x){ return x >= 0.f ? x : NEG_SLOPE * x; }

// ---------------- CSR build ----------------
// k_init: deg=1 (self loop) + fused int64/int32 edge-dtype detect (lane 0).
__global__ void k_init(const int* __restrict__ ei, int* __restrict__ flag,
                       int* __restrict__ deg){
  int i = blockIdx.x * blockDim.x + threadIdx.x;
  if (i == 0){
    int o = 0;
    #pragma unroll
    for (int j = 1; j < 16; j += 2) o |= ei[j];
    *flag = (o == 0) ? 1 : 0;  // 1 => int64 layout
  }
  if (i < N_NODES) deg[i] = 1;
}

// 2 edges per thread, vectorized dst reads.
__global__ void k_count(const int* __restrict__ ei, const int* __restrict__ flag,
                        int* __restrict__ deg){
  int t = blockIdx.x * blockDim.x + threadIdx.x;
  if (t >= N_EDGES / 2) return;
  int d0, d1;
  if (*flag){
    int4 dv = *(const int4*)&ei[2 * N_EDGES + 4 * t];
    d0 = dv.x; d1 = dv.z;
  } else {
    int2 dv = *(const int2*)&ei[N_EDGES + 2 * t];
    d0 = dv.x; d1 = dv.y;
  }
  atomicAdd(&deg[d0], 1);
  atomicAdd(&deg[d1], 1);
}

// block-scan: 49 blocks x 1024 elements (256 thr x 4)
__global__ void k_scan1(const int* __restrict__ deg, int* __restrict__ rowptr,
                        int* __restrict__ bsum){
  __shared__ int sd[256];
  int t = threadIdx.x;
  int base = blockIdx.x * 1024 + t * 4;
  int v0 = (base + 0 < N_NODES) ? deg[base + 0] : 0;
  int v1 = (base + 1 < N_NODES) ? deg[base + 1] : 0;
  int v2 = (base + 2 < N_NODES) ? deg[base + 2] : 0;
  int v3 = (base + 3 < N_NODES) ? deg[base + 3] : 0;
  int tsum = v0 + v1 + v2 + v3;
  sd[t] = tsum; __syncthreads();
  for (int off = 1; off < 256; off <<= 1){
    int vv = (t >= off) ? sd[t - off] : 0;
    __syncthreads();
    sd[t] += vv;
    __syncthreads();
  }
  int excl = sd[t] - tsum;
  if (base + 0 < N_NODES) rowptr[base + 0] = excl;
  if (base + 1 < N_NODES) rowptr[base + 1] = excl + v0;
  if (base + 2 < N_NODES) rowptr[base + 2] = excl + v0 + v1;
  if (base + 3 < N_NODES) rowptr[base + 3] = excl + v0 + v1 + v2;
  if (t == 255) bsum[blockIdx.x] = sd[255];
}

#define NB_SCAN 49
__global__ void k_scan2(const int* __restrict__ bsum, int* __restrict__ boff){
  int t = threadIdx.x;  // 64 threads, 1 block
  int v = (t < NB_SCAN) ? bsum[t] : 0;
  int incl = v;
  #pragma unroll
  for (int off = 1; off < 64; off <<= 1){
    int u = __shfl_up(incl, off);
    if (t >= off) incl += u;
  }
  if (t < NB_SCAN) boff[t] = incl - v;
}

// writes fill = rowptr so scatter needs no rowptr read (atomicAdd returns slot)
__global__ void k_scan3(int* __restrict__ rowptr, const int* __restrict__ boff,
                        int* __restrict__ fill){
  int i = blockIdx.x * blockDim.x + threadIdx.x;
  if (i < N_NODES){
    int v = rowptr[i] + boff[i >> 10];
    rowptr[i] = v;
    fill[i] = v;
  }
  if (i == 0) rowptr[N_NODES] = N_TOT;
}

// 2 edges per thread (vectorized src+dst reads); tail threads place self loops.
__global__ void k_scatter(const int* __restrict__ ei, const int* __restrict__ flag,
                          int* __restrict__ fill, int* __restrict__ col){
  int t = blockIdx.x * blockDim.x + threadIdx.x;
  if (t < N_EDGES / 2){
    int s0, s1, d0, d1;
    if (*flag){
      int4 sv = *(const int4*)&ei[4 * t];
      int4 dv = *(const int4*)&ei[2 * N_EDGES + 4 * t];
      s0 = sv.x; s1 = sv.z; d0 = dv.x; d1 = dv.z;
    } else {
      int2 sv = *(const int2*)&ei[2 * t];
      int2 dv = *(const int2*)&ei[N_EDGES + 2 * t];
      s0 = sv.x; s1 = sv.y; d0 = dv.x; d1 = dv.y;
    }
    col[atomicAdd(&fill[d0], 1)] = s0;
    col[atomicAdd(&fill[d1], 1)] = s1;
  } else {
    int n = t - N_EDGES / 2;
    if (n < N_NODES) col[atomicAdd(&fill[n], 1)] = n;   // self loop
  }
}

// ---------------- feature transforms ----------------
// h is stored as fp16 (halves gather bytes in k_agg); es/ed computed from the
// unrounded f32 accumulators so attention coefficients stay near-exact.

// layer 1: x[N,8] @ W[8,256] -> h[N,256] (fp16); e_src/e_dst[N,4] (f32)
__global__ __launch_bounds__(256) void k_transform1(
    const float* __restrict__ xin, const float* __restrict__ W,
    const float* __restrict__ aS, const float* __restrict__ aD,
    __half* __restrict__ h, float* __restrict__ es, float* __restrict__ ed){
  __shared__ float wl[8 * 256];
  int tid = threadIdx.x;
  for (int i = tid; i < 8 * 256; i += 256) wl[i] = W[i];
  int lane = tid & 63, wv = tid >> 6, head = lane >> 4;
  float4 s4 = *(const float4*)&aS[4 * lane];
  float4 d4 = *(const float4*)&aD[4 * lane];
  __syncthreads();
  int base = (blockIdx.x * 4 + wv) * 8;   // 8 nodes per wave
  for (int m = 0; m < 8; m++){
    int n = base + m;
    if (n >= N_NODES) break;
    float4 xa = *(const float4*)&xin[n * 8];
    float4 xb = *(const float4*)&xin[n * 8 + 4];
    float xs0 = xa.x, xs1 = xa.y, xs2 = xa.z, xs3 = xa.w;
    float xs4 = xb.x, xs5 = xb.y, xs6 = xb.z, xs7 = xb.w;
    float4 acc = make_float4(0.f, 0.f, 0.f, 0.f);
    #define T1STEP(k, xv) { float4 w4 = *(const float4*)&wl[(k)*256 + 4*lane]; \
      acc.x = fmaf(xv, w4.x, acc.x); acc.y = fmaf(xv, w4.y, acc.y); \
      acc.z = fmaf(xv, w4.z, acc.z); acc.w = fmaf(xv, w4.w, acc.w); }
    T1STEP(0, xs0) T1STEP(1, xs1) T1STEP(2, xs2) T1STEP(3, xs3)
    T1STEP(4, xs4) T1STEP(5, xs5) T1STEP(6, xs6) T1STEP(7, xs7)
    #undef T1STEP
    __half2 p0 = __floats2half2_rn(acc.x, acc.y);
    __half2 p1 = __floats2half2_rn(acc.z, acc.w);
    uint2 u; u.x = *(unsigned int*)&p0; u.y = *(unsigned int*)&p1;
    *(uint2*)&h[(size_t)n * 256 + 4 * lane] = u;
    float ps = acc.x*s4.x + acc.y*s4.y + acc.z*s4.z + acc.w*s4.w;
    float pd = acc.x*d4.x + acc.y*d4.y + acc.z*d4.z + acc.w*d4.w;
    #pragma unroll
    for (int off = 1; off < 16; off <<= 1){ ps += __shfl_xor(ps, off); pd += __shfl_xor(pd, off); }
    if ((lane & 15) == 0){ es[n * 4 + head] = ps; ed[n * 4 + head] = pd; }
  }
}

// layer 2: feat[N,64] @ W[64,256] -> h[N,256] (fp16); e_src/e_dst[N,4]
// Two-stage K over a 32 KiB LDS tile. Inner loop kept at unroll 4: full
// unroll spilled to scratch in R9 (VGPR 256, 1.2 GB spill writes, 35x slower).
__global__ __launch_bounds__(256) void k_transform2(
    const float* __restrict__ xin, const float* __restrict__ W,
    const float* __restrict__ aS, const float* __restrict__ aD,
    __half* __restrict__ h, float* __restrict__ es, float* __restrict__ ed){
  __shared__ float wl[32 * 256];   // 32 KiB
  int tid = threadIdx.x;
  int lane = tid & 63, wv = tid >> 6, head = lane >> 4;
  float4 s4 = *(const float4*)&aS[4 * lane];
  float4 d4 = *(const float4*)&aD[4 * lane];
  int base = (blockIdx.x * 4 + wv) * 8;   // 8 nodes per wave
  float xr[8];
  #pragma unroll
  for (int m = 0; m < 8; m++){
    int n = base + m;
    xr[m] = (n < N_NODES) ? xin[(size_t)n * 64 + lane] : 0.f;
  }
  float4 acc[8];
  #pragma unroll
  for (int m = 0; m < 8; m++) acc[m] = make_float4(0.f, 0.f, 0.f, 0.f);
  for (int hf = 0; hf < 2; hf++){
    if (hf) __syncthreads();   // all reads of previous half done
    const float4* Wv = (const float4*)(W + hf * 32 * 256);
    float4* wlv = (float4*)wl;
    #pragma unroll
    for (int i = 0; i < 8; i++) wlv[tid + 256 * i] = Wv[tid + 256 * i];
    __syncthreads();
    #pragma unroll 4
    for (int k = 0; k < 32; k++){
      float4 w4 = *(const float4*)&wl[k * 256 + 4 * lane];
      #pragma unroll
      for (int m = 0; m < 8; m++){
        float xv = __shfl(xr[m], hf * 32 + k);
        acc[m].x = fmaf(xv, w4.x, acc[m].x);
        acc[m].y = fmaf(xv, w4.y, acc[m].y);
        acc[m].z = fmaf(xv, w4.z, acc[m].z);
        acc[m].w = fmaf(xv, w4.w, acc[m].w);
      }
    }
  }
  #pragma unroll
  for (int m = 0; m < 8; m++){
    int n = base + m;
    if (n >= N_NODES) break;
    __half2 p0 = __floats2half2_rn(acc[m].x, acc[m].y);
    __half2 p1 = __floats2half2_rn(acc[m].z, acc[m].w);
    uint2 u; u.x = *(unsigned int*)&p0; u.y = *(unsigned int*)&p1;
    *(uint2*)&h[(size_t)n * 256 + 4 * lane] = u;
    float ps = acc[m].x*s4.x + acc[m].y*s4.y + acc[m].z*s4.z + acc[m].w*s4.w;
    float pd = acc[m].x*d4.x + acc[m].y*d4.y + acc[m].z*d4.z + acc[m].w*d4.w;
    #pragma unroll
    for (int off = 1; off < 16; off <<= 1){ ps += __shfl_xor(ps, off); pd += __shfl_xor(pd, off); }
    if ((lane & 15) == 0){ es[n * 4 + head] = ps; ed[n * 4 + head] = pd; }
  }
}

// layer 3: feat[N,64] @ W3[64,1] -> pk[N]={es3,h3} (packed), ed3[N]
__global__ __launch_bounds__(256) void k_transform3(
    const float* __restrict__ xin, const float* __restrict__ W3,
    const float* __restrict__ aS, const float* __restrict__ aD,
    float2* __restrict__ pk, float* __restrict__ ed3){
  int gid = blockIdx.x * blockDim.x + threadIdx.x;
  int n = gid >> 6, lane = gid & 63;
  if (n >= N_NODES) return;
  float v = xin[(size_t)n * 64 + lane] * W3[lane];
  #pragma unroll
  for (int off = 1; off < 64; off <<= 1) v += __shfl_xor(v, off);
  if (lane == 0){
    pk[n] = make_float2(v * aS[0], v);   // (es3, h3) one 8B gather in agg3
    ed3[n] = v * aD[0];
  }
}

// ---------------- aggregation (layers 1,2): one wave per dst node ----------------
// No-max softmax (logits O(1-5) analytically; shift-invariant => identical math).
// 8-way unroll: 8 independent 1KB h-gathers + 8 es loads in flight per wave
// (latency-limited regime; R7 showed BW tracks requests-in-flight).
static __device__ __forceinline__ void agg_step(float4& acc, uint2 u, float wt){
  float2 aa = __half22float2(*(__half2*)&u.x);
  float2 bb = __half22float2(*(__half2*)&u.y);
  acc.x = fmaf(wt, aa.x, acc.x); acc.y = fmaf(wt, aa.y, acc.y);
  acc.z = fmaf(wt, bb.x, acc.z); acc.w = fmaf(wt, bb.y, acc.w);
}

__global__ __launch_bounds__(256) void k_agg(
    const __half* __restrict__ h, const float* __restrict__ es, const float* __restrict__ ed,
    const int* __restrict__ rowptr, const int* __restrict__ col,
    const float* __restrict__ bias, float* __restrict__ outf){
  int gid = blockIdx.x * blockDim.x + threadIdx.x;
  int d = gid >> 6, lane = gid & 63;
  if (d >= N_NODES) return;
  int start = rowptr[d], end = rowptr[d + 1];
  int head = lane >> 4;
  float eh = ed[d * 4 + head];          // 4 distinct addrs per wave, L2-hot
  const __half* hp = h + 4 * lane;
  float4 acc = make_float4(0.f, 0.f, 0.f, 0.f);
  float wsum = 0.f;
  int i = start;
  for (; i + 8 <= end; i += 8){
    int s0 = col[i],     s1 = col[i + 1], s2 = col[i + 2], s3 = col[i + 3];
    int s4 = col[i + 4], s5 = col[i + 5], s6 = col[i + 6], s7 = col[i + 7];
    uint2 u0 = *(const uint2*)(hp + (size_t)s0 * 256);
    uint2 u1 = *(const uint2*)(hp + (size_t)s1 * 256);
    uint2 u2 = *(const uint2*)(hp + (size_t)s2 * 256);
    uint2 u3 = *(const uint2*)(hp + (size_t)s3 * 256);
    uint2 u4 = *(const uint2*)(hp + (size_t)s4 * 256);
    uint2 u5 = *(const uint2*)(hp + (size_t)s5 * 256);
    uint2 u6 = *(const uint2*)(hp + (size_t)s6 * 256);
    uint2 u7 = *(const uint2*)(hp + (size_t)s7 * 256);
    float e0 = es[s0 * 4 + head], e1 = es[s1 * 4 + head];
    float e2 = es[s2 * 4 + head], e3 = es[s3 * 4 + head];
    float e4 = es[s4 * 4 + head], e5 = es[s5 * 4 + head];
    float e6 = es[s6 * 4 + head], e7 = es[s7 * 4 + head];
    float w0 = __expf(lrelu(e0 + eh)), w1 = __expf(lrelu(e1 + eh));
    float w2 = __expf(lrelu(e2 + eh)), w3 = __expf(lrelu(e3 + eh));
    float w4 = __expf(lrelu(e4 + eh)), w5 = __expf(lrelu(e5 + eh));
    float w6 = __expf(lrelu(e6 + eh)), w7 = __expf(lrelu(e7 + eh));
    wsum += ((w0 + w1) + (w2 + w3)) + ((w4 + w5) + (w6 + w7));
    agg_step(acc, u0, w0); agg_step(acc, u1, w1);
    agg_step(acc, u2, w2); agg_step(acc, u3, w3);
    agg_step(acc, u4, w4); agg_step(acc, u5, w5);
    agg_step(acc, u6, w6); agg_step(acc, u7, w7);
  }
  for (; i < end; i++){
    int s0 = col[i];
    uint2 u0 = *(const uint2*)(hp + (size_t)s0 * 256);
    float w0 = __expf(lrelu(es[s0 * 4 + head] + eh));
    wsum += w0;
    agg_step(acc, u0, w0);
  }
  float inv = 1.0f / (wsum + 1e-16f);
  acc.x *= inv; acc.y *= inv; acc.z *= inv; acc.w *= inv;
  // mean over heads: sum lanes differing in bits 4,5
  #pragma unroll
  for (int off = 16; off < 64; off <<= 1){
    acc.x += __shfl_xor(acc.x, off);
    acc.y += __shfl_xor(acc.y, off);
    acc.z += __shfl_xor(acc.z, off);
    acc.w += __shfl_xor(acc.w, off);
  }
  if (lane < 16){
    float4 b4 = *(const float4*)&bias[4 * lane];
    float ox = 0.25f * acc.x + b4.x;
    float oy = 0.25f * acc.y + b4.y;
    float oz = 0.25f * acc.z + b4.z;
    float ow = 0.25f * acc.w + b4.w;
    ox = ox > 0.f ? ox : expm1f(ox);   // ELU
    oy = oy > 0.f ? oy : expm1f(oy);
    oz = oz > 0.f ? oz : expm1f(oz);
    ow = ow > 0.f ? ow : expm1f(ow);
    float4 o = make_float4(ox, oy, oz, ow);
    *(float4*)&outf[(size_t)d * 64 + 4 * lane] = o;
  }
}

// ---------------- aggregation layer 3 (1 head, 1 channel) + sigmoid ----------------
// 4 nodes per wave, 16 lanes each; packed (es3,h3) => one 8B gather per edge.
__global__ __launch_bounds__(256) void k_agg3(
    const float2* __restrict__ pk, const float* __restrict__ ed3,
    const int* __restrict__ rowptr, const int* __restrict__ col,
    const float* __restrict__ b3, float* __restrict__ out){
  int gid = blockIdx.x * blockDim.x + threadIdx.x;
  int wv = gid >> 6, lane = gid & 63;
  int sub = lane >> 4, li = lane & 15;
  int d = wv * 4 + sub;
  if (d < N_NODES){
    int start = rowptr[d], end = rowptr[d + 1];
    float edv = ed3[d];
    float num = 0.f, den = 0.f;
    for (int i = start + li; i < end; i += 16){
      float2 p = pk[col[i]];
      float wgt = __expf(lrelu(p.x + edv));   // no-max softmax
      den += wgt;
      num = fmaf(wgt, p.y, num);
    }
    #pragma unroll
    for (int off = 1; off < 16; off <<= 1){
      num += __shfl_xor(num, off);
      den += __shfl_xor(den, off);
    }
    if (li == 0){
      float v = num / (den + 1e-16f) + b3[0];
      out[d] = 1.f / (1.f + __expf(-v));
    }
  }
}

// ---------------- launcher ----------------
extern "C" void kernel_launch(void* const* d_in, const int* in_sizes, int n_in,
                              void* d_out, int out_size, void* d_ws, size_t ws_size,
                              hipStream_t stream) {
  const float* x   = (const float*)d_in[0];
  const int*   ei  = (const int*)  d_in[1];
  const float* W1  = (const float*)d_in[2];
  const float* b1  = (const float*)d_in[3];
  const float* as1 = (const float*)d_in[4];
  const float* ad1 = (const float*)d_in[5];
  const float* W2  = (const float*)d_in[6];
  const float* b2  = (const float*)d_in[7];
  const float* as2 = (const float*)d_in[8];
  const float* ad2 = (const float*)d_in[9];
  const float* W3  = (const float*)d_in[10];
  const float* b3  = (const float*)d_in[11];
  const float* as3 = (const float*)d_in[12];
  const float* ad3 = (const float*)d_in[13];
  float* out = (float*)d_out;

  // workspace layout (all offsets 256B-aligned)
  char* w = (char*)d_ws;
  size_t off = 0;
  auto alloc = [&](size_t bytes) -> char* {
    char* p = w + off;
    off += (bytes + 255) & ~size_t(255);
    return p;
  };
  int*    flag   = (int*)   alloc(64);
  int*    deg    = (int*)   alloc(N_NODES * 4);
  int*    fill   = (int*)   alloc(N_NODES * 4);
  int*    rowptr = (int*)   alloc((N_NODES + 1) * 4);
  int*    bsum   = (int*)   alloc(64 * 4);
  int*    boff   = (int*)   alloc(64 * 4);
  int*    col    = (int*)   alloc((size_t)N_TOT * 4);
  __half* h      = (__half*)alloc((size_t)N_NODES * 256 * 2);  // 25.6 MB fp16
  float*  es     = (float*) alloc((size_t)N_NODES * 4 * 4);
  float*  ed     = (float*) alloc((size_t)N_NODES * 4 * 4);
  float*  feat1  = (float*) alloc((size_t)N_NODES * 64 * 4);   // 12.8 MB
  float*  feat2  = (float*) alloc((size_t)N_NODES * 64 * 4);   // 12.8 MB
  float2* pk     = (float2*)alloc((size_t)N_NODES * 8);
  float*  ed3    = (float*) alloc(N_NODES * 4);
  (void)ws_size; (void)in_sizes; (void)n_in; (void)out_size;

  // ---- CSR build (shared by all 3 layers) ----
  k_init   <<<(N_NODES + 255) / 256, 256, 0, stream>>>(ei, flag, deg);
  k_count  <<<(N_EDGES / 2 + 255) / 256, 256, 0, stream>>>(ei, flag, deg);
  k_scan1  <<<NB_SCAN, 256, 0, stream>>>(deg, rowptr, bsum);
  k_scan2  <<<1, 64, 0, stream>>>(bsum, boff);
  k_scan3  <<<(N_NODES + 255) / 256, 256, 0, stream>>>(rowptr, boff, fill);
  k_scatter<<<(N_EDGES / 2 + N_NODES + 255) / 256, 256, 0, stream>>>(ei, flag, fill, col);

  const int grid_t12 = (N_NODES + 31) / 32;        // 8 nodes/wave * 4 waves
  const int grid_wpn = (N_NODES * 64 + 255) / 256; // wave per node
  const int grid_w4n = ((N_NODES + 3) / 4 * 64 + 255) / 256; // 4 nodes per wave

  // ---- layer 1 ----
  k_transform1<<<grid_t12, 256, 0, stream>>>(x, W1, as1, ad1, h, es, ed);
  k_agg       <<<grid_wpn, 256, 0, stream>>>(h, es, ed, rowptr, col, b1, feat1);
  // ---- layer 2 ----
  k_transform2<<<grid_t12, 256, 0, stream>>>(feat1, W2, as2, ad2, h, es, ed);
  k_agg       <<<grid_wpn, 256, 0, stream>>>(h, es, ed, rowptr, col, b2, feat2);
  // ---- layer 3 ----
  k_transform3<<<grid_wpn, 256, 0, stream>>>(feat2, W3, as3, ad3, pk, ed3);
  k_agg3      <<<grid_w4n, 256, 0, stream>>>(pk, ed3, rowptr, col, b3, out);
}

// Round 12
// 394.023 us; speedup vs baseline: 3.2012x; 1.0373x over previous
//
#include <hip/hip_runtime.h>
#include <hip/hip_bf16.h>
#include <hip/hip_fp16.h>
#include <math.h>

// Problem constants (from reference)
#define N_NODES 50000
#define N_EDGES 800000
#define N_TOT   (N_EDGES + N_NODES)  // 850000 edges incl. self loops
#define NEG_SLOPE 0.2f

static __device__ __forceinline__ float lrelu(float x){ return x >= 0.f ? x : NEG_SLOPE * x; }

// ---------------- CSR build ----------------
// k_init: deg=1 (self loop) + fused int64/int32 edge-dtype detect (lane 0).
__global__ void k_init(const int* __restrict__ ei, int* __restrict__ flag,
                       int* __restrict__ deg){
  int i = blockIdx.x * blockDim.x + threadIdx.x;
  if (i == 0){
    int o = 0;
    #pragma unroll
    for (int j = 1; j < 16; j += 2) o |= ei[j];
    *flag = (o == 0) ? 1 : 0;  // 1 => int64 layout
  }
  if (i < N_NODES) deg[i] = 1;
}

// 4 edges per thread, int4-vectorized dst reads.
__global__ void k_count(const int* __restrict__ ei, const int* __restrict__ flag,
                        int* __restrict__ deg){
  int t = blockIdx.x * blockDim.x + threadIdx.x;
  if (t >= N_EDGES / 4) return;
  int d0, d1, d2, d3;
  if (*flag){
    int4 a = *(const int4*)&ei[2 * N_EDGES + 8 * t];
    int4 b = *(const int4*)&ei[2 * N_EDGES + 8 * t + 4];
    d0 = a.x; d1 = a.z; d2 = b.x; d3 = b.z;
  } else {
    int4 a = *(const int4*)&ei[N_EDGES + 4 * t];
    d0 = a.x; d1 = a.y; d2 = a.z; d3 = a.w;
  }
  atomicAdd(&deg[d0], 1);
  atomicAdd(&deg[d1], 1);
  atomicAdd(&deg[d2], 1);
  atomicAdd(&deg[d3], 1);
}

// block-scan: 49 blocks x 1024 elements (256 thr x 4)
__global__ void k_scan1(const int* __restrict__ deg, int* __restrict__ rowptr,
                        int* __restrict__ bsum){
  __shared__ int sd[256];
  int t = threadIdx.x;
  int base = blockIdx.x * 1024 + t * 4;
  int v0 = (base + 0 < N_NODES) ? deg[base + 0] : 0;
  int v1 = (base + 1 < N_NODES) ? deg[base + 1] : 0;
  int v2 = (base + 2 < N_NODES) ? deg[base + 2] : 0;
  int v3 = (base + 3 < N_NODES) ? deg[base + 3] : 0;
  int tsum = v0 + v1 + v2 + v3;
  sd[t] = tsum; __syncthreads();
  for (int off = 1; off < 256; off <<= 1){
    int vv = (t >= off) ? sd[t - off] : 0;
    __syncthreads();
    sd[t] += vv;
    __syncthreads();
  }
  int excl = sd[t] - tsum;
  if (base + 0 < N_NODES) rowptr[base + 0] = excl;
  if (base + 1 < N_NODES) rowptr[base + 1] = excl + v0;
  if (base + 2 < N_NODES) rowptr[base + 2] = excl + v0 + v1;
  if (base + 3 < N_NODES) rowptr[base + 3] = excl + v0 + v1 + v2;
  if (t == 255) bsum[blockIdx.x] = sd[255];
}

#define NB_SCAN 49
// scan of the 49 block sums folded in (each block's wave 0 redundantly
// shfl-scans bsum — removes the separate k_scan2 launch);
// writes fill = rowptr so scatter needs no rowptr read.
__global__ void k_scan3(int* __restrict__ rowptr, const int* __restrict__ bsum,
                        int* __restrict__ fill){
  __shared__ int sboff[64];
  int t = threadIdx.x;
  if (t < 64){
    int v = (t < NB_SCAN) ? bsum[t] : 0;
    int incl = v;
    #pragma unroll
    for (int off = 1; off < 64; off <<= 1){
      int u = __shfl_up(incl, off);
      if (t >= off) incl += u;
    }
    sboff[t] = incl - v;
  }
  __syncthreads();
  int i = blockIdx.x * blockDim.x + t;
  if (i < N_NODES){
    int v = rowptr[i] + sboff[i >> 10];
    rowptr[i] = v;
    fill[i] = v;
  }
  if (i == 0) rowptr[N_NODES] = N_TOT;
}

// 4 edges per thread (int4 src+dst reads); tail threads place self loops.
__global__ void k_scatter(const int* __restrict__ ei, const int* __restrict__ flag,
                          int* __restrict__ fill, int* __restrict__ col){
  int t = blockIdx.x * blockDim.x + threadIdx.x;
  if (t < N_EDGES / 4){
    int s0, s1, s2, s3, d0, d1, d2, d3;
    if (*flag){
      int4 sa = *(const int4*)&ei[8 * t];
      int4 sb = *(const int4*)&ei[8 * t + 4];
      int4 da = *(const int4*)&ei[2 * N_EDGES + 8 * t];
      int4 db = *(const int4*)&ei[2 * N_EDGES + 8 * t + 4];
      s0 = sa.x; s1 = sa.z; s2 = sb.x; s3 = sb.z;
      d0 = da.x; d1 = da.z; d2 = db.x; d3 = db.z;
    } else {
      int4 sa = *(const int4*)&ei[4 * t];
      int4 da = *(const int4*)&ei[N_EDGES + 4 * t];
      s0 = sa.x; s1 = sa.y; s2 = sa.z; s3 = sa.w;
      d0 = da.x; d1 = da.y; d2 = da.z; d3 = da.w;
    }
    col[atomicAdd(&fill[d0], 1)] = s0;
    col[atomicAdd(&fill[d1], 1)] = s1;
    col[atomicAdd(&fill[d2], 1)] = s2;
    col[atomicAdd(&fill[d3], 1)] = s3;
  } else {
    int n = t - N_EDGES / 4;
    if (n < N_NODES) col[atomicAdd(&fill[n], 1)] = n;   // self loop
  }
}

// ---------------- feature transforms ----------------
// h is stored as fp16 (halves gather bytes in k_agg); es/ed computed from the
// unrounded f32 accumulators so attention coefficients stay near-exact.

// layer 1: x[N,8] @ W[8,256] -> h[N,256] (fp16); e_src/e_dst[N,4] (f32)
__global__ __launch_bounds__(256) void k_transform1(
    const float* __restrict__ xin, const float* __restrict__ W,
    const float* __restrict__ aS, const float* __restrict__ aD,
    __half* __restrict__ h, float* __restrict__ es, float* __restrict__ ed){
  __shared__ float wl[8 * 256];
  int tid = threadIdx.x;
  for (int i = tid; i < 8 * 256; i += 256) wl[i] = W[i];
  int lane = tid & 63, wv = tid >> 6, head = lane >> 4;
  float4 s4 = *(const float4*)&aS[4 * lane];
  float4 d4 = *(const float4*)&aD[4 * lane];
  __syncthreads();
  int base = (blockIdx.x * 4 + wv) * 8;   // 8 nodes per wave
  for (int m = 0; m < 8; m++){
    int n = base + m;
    if (n >= N_NODES) break;
    float4 xa = *(const float4*)&xin[n * 8];
    float4 xb = *(const float4*)&xin[n * 8 + 4];
    float xs0 = xa.x, xs1 = xa.y, xs2 = xa.z, xs3 = xa.w;
    float xs4 = xb.x, xs5 = xb.y, xs6 = xb.z, xs7 = xb.w;
    float4 acc = make_float4(0.f, 0.f, 0.f, 0.f);
    #define T1STEP(k, xv) { float4 w4 = *(const float4*)&wl[(k)*256 + 4*lane]; \
      acc.x = fmaf(xv, w4.x, acc.x); acc.y = fmaf(xv, w4.y, acc.y); \
      acc.z = fmaf(xv, w4.z, acc.z); acc.w = fmaf(xv, w4.w, acc.w); }
    T1STEP(0, xs0) T1STEP(1, xs1) T1STEP(2, xs2) T1STEP(3, xs3)
    T1STEP(4, xs4) T1STEP(5, xs5) T1STEP(6, xs6) T1STEP(7, xs7)
    #undef T1STEP
    __half2 p0 = __floats2half2_rn(acc.x, acc.y);
    __half2 p1 = __floats2half2_rn(acc.z, acc.w);
    uint2 u; u.x = *(unsigned int*)&p0; u.y = *(unsigned int*)&p1;
    *(uint2*)&h[(size_t)n * 256 + 4 * lane] = u;
    float ps = acc.x*s4.x + acc.y*s4.y + acc.z*s4.z + acc.w*s4.w;
    float pd = acc.x*d4.x + acc.y*d4.y + acc.z*d4.z + acc.w*d4.w;
    #pragma unroll
    for (int off = 1; off < 16; off <<= 1){ ps += __shfl_xor(ps, off); pd += __shfl_xor(pd, off); }
    if ((lane & 15) == 0){ es[n * 4 + head] = ps; ed[n * 4 + head] = pd; }
  }
}

// layer 2: feat[N,64] @ W[64,256] -> h[N,256] (fp16); e_src/e_dst[N,4]
// Two-stage K over a 32 KiB LDS tile. Inner loop kept at unroll 4: full
// unroll spilled to scratch in R9 (VGPR 256, 1.2 GB spill writes, 35x slower).
__global__ __launch_bounds__(256) void k_transform2(
    const float* __restrict__ xin, const float* __restrict__ W,
    const float* __restrict__ aS, const float* __restrict__ aD,
    __half* __restrict__ h, float* __restrict__ es, float* __restrict__ ed){
  __shared__ float wl[32 * 256];   // 32 KiB
  int tid = threadIdx.x;
  int lane = tid & 63, wv = tid >> 6, head = lane >> 4;
  float4 s4 = *(const float4*)&aS[4 * lane];
  float4 d4 = *(const float4*)&aD[4 * lane];
  int base = (blockIdx.x * 4 + wv) * 8;   // 8 nodes per wave
  float xr[8];
  #pragma unroll
  for (int m = 0; m < 8; m++){
    int n = base + m;
    xr[m] = (n < N_NODES) ? xin[(size_t)n * 64 + lane] : 0.f;
  }
  float4 acc[8];
  #pragma unroll
  for (int m = 0; m < 8; m++) acc[m] = make_float4(0.f, 0.f, 0.f, 0.f);
  for (int hf = 0; hf < 2; hf++){
    if (hf) __syncthreads();   // all reads of previous half done
    const float4* Wv = (const float4*)(W + hf * 32 * 256);
    float4* wlv = (float4*)wl;
    #pragma unroll
    for (int i = 0; i < 8; i++) wlv[tid + 256 * i] = Wv[tid + 256 * i];
    __syncthreads();
    #pragma unroll 4
    for (int k = 0; k < 32; k++){
      float4 w4 = *(const float4*)&wl[k * 256 + 4 * lane];
      #pragma unroll
      for (int m = 0; m < 8; m++){
        float xv = __shfl(xr[m], hf * 32 + k);
        acc[m].x = fmaf(xv, w4.x, acc[m].x);
        acc[m].y = fmaf(xv, w4.y, acc[m].y);
        acc[m].z = fmaf(xv, w4.z, acc[m].z);
        acc[m].w = fmaf(xv, w4.w, acc[m].w);
      }
    }
  }
  #pragma unroll
  for (int m = 0; m < 8; m++){
    int n = base + m;
    if (n >= N_NODES) break;
    __half2 p0 = __floats2half2_rn(acc[m].x, acc[m].y);
    __half2 p1 = __floats2half2_rn(acc[m].z, acc[m].w);
    uint2 u; u.x = *(unsigned int*)&p0; u.y = *(unsigned int*)&p1;
    *(uint2*)&h[(size_t)n * 256 + 4 * lane] = u;
    float ps = acc[m].x*s4.x + acc[m].y*s4.y + acc[m].z*s4.z + acc[m].w*s4.w;
    float pd = acc[m].x*d4.x + acc[m].y*d4.y + acc[m].z*d4.z + acc[m].w*d4.w;
    #pragma unroll
    for (int off = 1; off < 16; off <<= 1){ ps += __shfl_xor(ps, off); pd += __shfl_xor(pd, off); }
    if ((lane & 15) == 0){ es[n * 4 + head] = ps; ed[n * 4 + head] = pd; }
  }
}

// layer 3: feat[N,64] @ W3[64,1] -> pk[N]={es3,h3} (packed), ed3[N]
__global__ __launch_bounds__(256) void k_transform3(
    const float* __restrict__ xin, const float* __restrict__ W3,
    const float* __restrict__ aS, const float* __restrict__ aD,
    float2* __restrict__ pk, float* __restrict__ ed3){
  int gid = blockIdx.x * blockDim.x + threadIdx.x;
  int n = gid >> 6, lane = gid & 63;
  if (n >= N_NODES) return;
  float v = xin[(size_t)n * 64 + lane] * W3[lane];
  #pragma unroll
  for (int off = 1; off < 64; off <<= 1) v += __shfl_xor(v, off);
  if (lane == 0){
    pk[n] = make_float2(v * aS[0], v);   // (es3, h3) one 8B gather in agg3
    ed3[n] = v * aD[0];
  }
}

// ---------------- aggregation (layers 1,2): one wave per dst node ----------------
// No-max softmax (logits O(1-5) analytically; shift-invariant => identical math).
// 4-way unroll is the measured sweet spot: R7 (4x, 24 VGPR, 68% occ) = 68 us;
// R11 (8x, 36 VGPR, 58% occ) = 71.4 us — TLP loss beat the extra ILP.
static __device__ __forceinline__ void agg_step(float4& acc, uint2 u, float wt){
  float2 aa = __half22float2(*(__half2*)&u.x);
  float2 bb = __half22float2(*(__half2*)&u.y);
  acc.x = fmaf(wt, aa.x, acc.x); acc.y = fmaf(wt, aa.y, acc.y);
  acc.z = fmaf(wt, bb.x, acc.z); acc.w = fmaf(wt, bb.y, acc.w);
}

__global__ __launch_bounds__(256) void k_agg(
    const __half* __restrict__ h, const float* __restrict__ es, const float* __restrict__ ed,
    const int* __restrict__ rowptr, const int* __restrict__ col,
    const float* __restrict__ bias, float* __restrict__ outf){
  int gid = blockIdx.x * blockDim.x + threadIdx.x;
  int d = gid >> 6, lane = gid & 63;
  if (d >= N_NODES) return;
  int start = rowptr[d], end = rowptr[d + 1];
  int head = lane >> 4;
  float eh = ed[d * 4 + head];          // 4 distinct addrs per wave, L2-hot
  const __half* hp = h + 4 * lane;
  float4 acc = make_float4(0.f, 0.f, 0.f, 0.f);
  float wsum = 0.f;
  int i = start;
  for (; i + 4 <= end; i += 4){
    int s0 = col[i], s1 = col[i + 1], s2 = col[i + 2], s3 = col[i + 3];
    uint2 u0 = *(const uint2*)(hp + (size_t)s0 * 256);
    uint2 u1 = *(const uint2*)(hp + (size_t)s1 * 256);
    uint2 u2 = *(const uint2*)(hp + (size_t)s2 * 256);
    uint2 u3 = *(const uint2*)(hp + (size_t)s3 * 256);
    float e0 = es[s0 * 4 + head], e1 = es[s1 * 4 + head];
    float e2 = es[s2 * 4 + head], e3 = es[s3 * 4 + head];
    float w0 = __expf(lrelu(e0 + eh));
    float w1 = __expf(lrelu(e1 + eh));
    float w2 = __expf(lrelu(e2 + eh));
    float w3 = __expf(lrelu(e3 + eh));
    wsum += (w0 + w1) + (w2 + w3);
    agg_step(acc, u0, w0); agg_step(acc, u1, w1);
    agg_step(acc, u2, w2); agg_step(acc, u3, w3);
  }
  for (; i < end; i++){
    int s0 = col[i];
    uint2 u0 = *(const uint2*)(hp + (size_t)s0 * 256);
    float w0 = __expf(lrelu(es[s0 * 4 + head] + eh));
    wsum += w0;
    agg_step(acc, u0, w0);
  }
  float inv = 1.0f / (wsum + 1e-16f);
  acc.x *= inv; acc.y *= inv; acc.z *= inv; acc.w *= inv;
  // mean over heads: sum lanes differing in bits 4,5
  #pragma unroll
  for (int off = 16; off < 64; off <<= 1){
    acc.x += __shfl_xor(acc.x, off);
    acc.y += __shfl_xor(acc.y, off);
    acc.z += __shfl_xor(acc.z, off);
    acc.w += __shfl_xor(acc.w, off);
  }
  if (lane < 16){
    float4 b4 = *(const float4*)&bias[4 * lane];
    float ox = 0.25f * acc.x + b4.x;
    float oy = 0.25f * acc.y + b4.y;
    float oz = 0.25f * acc.z + b4.z;
    float ow = 0.25f * acc.w + b4.w;
    ox = ox > 0.f ? ox : expm1f(ox);   // ELU
    oy = oy > 0.f ? oy : expm1f(oy);
    oz = oz > 0.f ? oz : expm1f(oz);
    ow = ow > 0.f ? ow : expm1f(ow);
    float4 o = make_float4(ox, oy, oz, ow);
    *(float4*)&outf[(size_t)d * 64 + 4 * lane] = o;
  }
}

// ---------------- aggregation layer 3 (1 head, 1 channel) + sigmoid ----------------
// 4 nodes per wave, 16 lanes each; packed (es3,h3) => one 8B gather per edge.
__global__ __launch_bounds__(256) void k_agg3(
    const float2* __restrict__ pk, const float* __restrict__ ed3,
    const int* __restrict__ rowptr, const int* __restrict__ col,
    const float* __restrict__ b3, float* __restrict__ out){
  int gid = blockIdx.x * blockDim.x + threadIdx.x;
  int wv = gid >> 6, lane = gid & 63;
  int sub = lane >> 4, li = lane & 15;
  int d = wv * 4 + sub;
  if (d < N_NODES){
    int start = rowptr[d], end = rowptr[d + 1];
    float edv = ed3[d];
    float num = 0.f, den = 0.f;
    for (int i = start + li; i < end; i += 16){
      float2 p = pk[col[i]];
      float wgt = __expf(lrelu(p.x + edv));   // no-max softmax
      den += wgt;
      num = fmaf(wgt, p.y, num);
    }
    #pragma unroll
    for (int off = 1; off < 16; off <<= 1){
      num += __shfl_xor(num, off);
      den += __shfl_xor(den, off);
    }
    if (li == 0){
      float v = num / (den + 1e-16f) + b3[0];
      out[d] = 1.f / (1.f + __expf(-v));
    }
  }
}

// ---------------- launcher ----------------
extern "C" void kernel_launch(void* const* d_in, const int* in_sizes, int n_in,
                              void* d_out, int out_size, void* d_ws, size_t ws_size,
                              hipStream_t stream) {
  const float* x   = (const float*)d_in[0];
  const int*   ei  = (const int*)  d_in[1];
  const float* W1  = (const float*)d_in[2];
  const float* b1  = (const float*)d_in[3];
  const float* as1 = (const float*)d_in[4];
  const float* ad1 = (const float*)d_in[5];
  const float* W2  = (const float*)d_in[6];
  const float* b2  = (const float*)d_in[7];
  const float* as2 = (const float*)d_in[8];
  const float* ad2 = (const float*)d_in[9];
  const float* W3  = (const float*)d_in[10];
  const float* b3  = (const float*)d_in[11];
  const float* as3 = (const float*)d_in[12];
  const float* ad3 = (const float*)d_in[13];
  float* out = (float*)d_out;

  // workspace layout (all offsets 256B-aligned)
  char* w = (char*)d_ws;
  size_t off = 0;
  auto alloc = [&](size_t bytes) -> char* {
    char* p = w + off;
    off += (bytes + 255) & ~size_t(255);
    return p;
  };
  int*    flag   = (int*)   alloc(64);
  int*    deg    = (int*)   alloc(N_NODES * 4);
  int*    fill   = (int*)   alloc(N_NODES * 4);
  int*    rowptr = (int*)   alloc((N_NODES + 1) * 4);
  int*    bsum   = (int*)   alloc(64 * 4);
  int*    col    = (int*)   alloc((size_t)N_TOT * 4);
  __half* h      = (__half*)alloc((size_t)N_NODES * 256 * 2);  // 25.6 MB fp16
  float*  es     = (float*) alloc((size_t)N_NODES * 4 * 4);
  float*  ed     = (float*) alloc((size_t)N_NODES * 4 * 4);
  float*  feat1  = (float*) alloc((size_t)N_NODES * 64 * 4);   // 12.8 MB
  float*  feat2  = (float*) alloc((size_t)N_NODES * 64 * 4);   // 12.8 MB
  float2* pk     = (float2*)alloc((size_t)N_NODES * 8);
  float*  ed3    = (float*) alloc(N_NODES * 4);
  (void)ws_size; (void)in_sizes; (void)n_in; (void)out_size;

  // ---- CSR build (shared by all 3 layers); 5 launches ----
  k_init   <<<(N_NODES + 255) / 256, 256, 0, stream>>>(ei, flag, deg);
  k_count  <<<(N_EDGES / 4 + 255) / 256, 256, 0, stream>>>(ei, flag, deg);
  k_scan1  <<<NB_SCAN, 256, 0, stream>>>(deg, rowptr, bsum);
  k_scan3  <<<(N_NODES + 255) / 256, 256, 0, stream>>>(rowptr, bsum, fill);
  k_scatter<<<(N_EDGES / 4 + N_NODES + 255) / 256, 256, 0, stream>>>(ei, flag, fill, col);

  const int grid_t12 = (N_NODES + 31) / 32;        // 8 nodes/wave * 4 waves
  const int grid_wpn = (N_NODES * 64 + 255) / 256; // wave per node
  const int grid_w4n = ((N_NODES + 3) / 4 * 64 + 255) / 256; // 4 nodes per wave

  // ---- layer 1 ----
  k_transform1<<<grid_t12, 256, 0, stream>>>(x, W1, as1, ad1, h, es, ed);
  k_agg       <<<grid_wpn, 256, 0, stream>>>(h, es, ed, rowptr, col, b1, feat1);
  // ---- layer 2 ----
  k_transform2<<<grid_t12, 256, 0, stream>>>(feat1, W2, as2, ad2, h, es, ed);
  k_agg       <<<grid_wpn, 256, 0, stream>>>(h, es, ed, rowptr, col, b2, feat2);
  // ---- layer 3 ----
  k_transform3<<<grid_wpn, 256, 0, stream>>>(feat2, W3, as3, ad3, pk, ed3);
  k_agg3      <<<grid_w4n, 256, 0, stream>>>(pk, ed3, rowptr, col, b3, out);
}

// Round 14
// 385.004 us; speedup vs baseline: 3.2762x; 1.0234x over previous
//
#include <hip/hip_runtime.h>
#include <hip/hip_fp16.h>
#include <math.h>

// Problem constants (from reference)
#define N_NODES 50000
#define N_EDGES 800000
#define N_TOT   (N_EDGES + N_NODES)  // 850000 edges incl. self loops
#define NEG_SLOPE 0.2f
#define NB_COUNT 782   // ceil((N_EDGES/4)/256)
#define NB_SCAN  49    // ceil(N_NODES/1024)

static __device__ __forceinline__ float lrelu(float x){ return x >= 0.f ? x : NEG_SLOPE * x; }

// int64 vs int32 edge layout: odd 32-bit words all-zero => int64 (values < 50000).
// One 64B line, broadcast-cached — effectively free per thread.
static __device__ __forceinline__ int edge_flag(const int* __restrict__ ei){
  int o = 0;
  #pragma unroll
  for (int j = 1; j < 16; j += 2) o |= ei[j];
  return (o == 0) ? 1 : 0;
}

// ---------------- kA: k_count (blocks [0,NB_COUNT)) ∥ k_transform1 (rest) ----
// Independent workloads fused by block-split: count's random atomics overlap
// transform1's streaming on different CUs. deg pre-zeroed by hipMemsetAsync.
__global__ __launch_bounds__(256) void kA(
    const int* __restrict__ ei, int* __restrict__ deg,
    const float* __restrict__ xin, const float* __restrict__ W,
    const float* __restrict__ aS, const float* __restrict__ aD,
    __half* __restrict__ h, float* __restrict__ es, float* __restrict__ ed){
  __shared__ float wl[8 * 256];
  if ((int)blockIdx.x < NB_COUNT){
    int t = blockIdx.x * 256 + threadIdx.x;
    if (t < N_EDGES / 4){
      int d0, d1, d2, d3;
      if (edge_flag(ei)){
        int4 a = *(const int4*)&ei[2 * N_EDGES + 8 * t];
        int4 b = *(const int4*)&ei[2 * N_EDGES + 8 * t + 4];
        d0 = a.x; d1 = a.z; d2 = b.x; d3 = b.z;
      } else {
        int4 a = *(const int4*)&ei[N_EDGES + 4 * t];
        d0 = a.x; d1 = a.y; d2 = a.z; d3 = a.w;
      }
      atomicAdd(&deg[d0], 1); atomicAdd(&deg[d1], 1);
      atomicAdd(&deg[d2], 1); atomicAdd(&deg[d3], 1);
    }
    return;
  }
  // ---- transform1: x[N,8] @ W[8,256] -> h fp16, es/ed f32 ----
  int bid = blockIdx.x - NB_COUNT;
  int tid = threadIdx.x;
  for (int i = tid; i < 8 * 256; i += 256) wl[i] = W[i];
  int lane = tid & 63, wv = tid >> 6, head = lane >> 4;
  float4 s4 = *(const float4*)&aS[4 * lane];
  float4 d4 = *(const float4*)&aD[4 * lane];
  __syncthreads();
  int base = (bid * 4 + wv) * 8;   // 8 nodes per wave
  for (int m = 0; m < 8; m++){
    int n = base + m;
    if (n >= N_NODES) break;
    float4 xa = *(const float4*)&xin[n * 8];
    float4 xb = *(const float4*)&xin[n * 8 + 4];
    float4 acc = make_float4(0.f, 0.f, 0.f, 0.f);
    #define T1STEP(k, xv) { float4 w4 = *(const float4*)&wl[(k)*256 + 4*lane]; \
      acc.x = fmaf(xv, w4.x, acc.x); acc.y = fmaf(xv, w4.y, acc.y); \
      acc.z = fmaf(xv, w4.z, acc.z); acc.w = fmaf(xv, w4.w, acc.w); }
    T1STEP(0, xa.x) T1STEP(1, xa.y) T1STEP(2, xa.z) T1STEP(3, xa.w)
    T1STEP(4, xb.x) T1STEP(5, xb.y) T1STEP(6, xb.z) T1STEP(7, xb.w)
    #undef T1STEP
    __half2 p0 = __floats2half2_rn(acc.x, acc.y);
    __half2 p1 = __floats2half2_rn(acc.z, acc.w);
    uint2 u; u.x = *(unsigned int*)&p0; u.y = *(unsigned int*)&p1;
    *(uint2*)&h[(size_t)n * 256 + 4 * lane] = u;
    float ps = acc.x*s4.x + acc.y*s4.y + acc.z*s4.z + acc.w*s4.w;
    float pd = acc.x*d4.x + acc.y*d4.y + acc.z*d4.z + acc.w*d4.w;
    #pragma unroll
    for (int off = 1; off < 16; off <<= 1){ ps += __shfl_xor(ps, off); pd += __shfl_xor(pd, off); }
    if ((lane & 15) == 0){ es[n * 4 + head] = ps; ed[n * 4 + head] = pd; }
  }
}

// ---------------- fused scan (was scan1+scan2+scan3) ----------------
// 49 blocks -> all co-resident on 256 CUs by construction, so a device-scope
// flag/spin barrier is deadlock-free. +1 per node folds in the self loop.
// Writes final rowptr AND fill (=rowptr) so scatter needs no rowptr read.
__global__ __launch_bounds__(256) void k_scan(
    const int* __restrict__ deg, int* __restrict__ rowptr, int* __restrict__ fill,
    int* __restrict__ bsum, int* __restrict__ done){
  __shared__ int sd[256];
  __shared__ int s_off;
  int b = blockIdx.x, t = threadIdx.x;
  int base = b * 1024 + t * 4;
  int v0 = (base + 0 < N_NODES) ? deg[base + 0] + 1 : 0;
  int v1 = (base + 1 < N_NODES) ? deg[base + 1] + 1 : 0;
  int v2 = (base + 2 < N_NODES) ? deg[base + 2] + 1 : 0;
  int v3 = (base + 3 < N_NODES) ? deg[base + 3] + 1 : 0;
  int tsum = v0 + v1 + v2 + v3;
  sd[t] = tsum; __syncthreads();
  for (int off = 1; off < 256; off <<= 1){
    int vv = (t >= off) ? sd[t - off] : 0;
    __syncthreads();
    sd[t] += vv;
    __syncthreads();
  }
  int excl = sd[t] - tsum;
  if (t == 255){
    atomicExch(&bsum[b], sd[255]);   // release: publish chunk total
    __threadfence();
    atomicAdd(done, 1);
  }
  if (t == 0){
    while (atomicAdd(done, 0) < NB_SCAN) { }   // spin until all published
  }
  __syncthreads();
  __threadfence();
  if (t < 64){                       // wave 0: off0 = sum of bsum[0..b)
    int u = (t < b) ? atomicAdd(&bsum[t], 0) : 0;
    #pragma unroll
    for (int off = 1; off < 64; off <<= 1) u += __shfl_xor(u, off);
    if (t == 0) s_off = u;
  }
  __syncthreads();
  int off0 = s_off;
  if (base + 0 < N_NODES){ int r = excl + off0;                rowptr[base+0] = r; fill[base+0] = r; }
  if (base + 1 < N_NODES){ int r = excl + v0 + off0;           rowptr[base+1] = r; fill[base+1] = r; }
  if (base + 2 < N_NODES){ int r = excl + v0 + v1 + off0;      rowptr[base+2] = r; fill[base+2] = r; }
  if (base + 3 < N_NODES){ int r = excl + v0 + v1 + v2 + off0; rowptr[base+3] = r; fill[base+3] = r; }
  if (b == 0 && t == 0) rowptr[N_NODES] = N_TOT;
}

// 4 edges per thread (int4 reads, inline flag); tail threads place self loops.
__global__ void k_scatter(const int* __restrict__ ei,
                          int* __restrict__ fill, int* __restrict__ col){
  int t = blockIdx.x * blockDim.x + threadIdx.x;
  if (t < N_EDGES / 4){
    int s0, s1, s2, s3, d0, d1, d2, d3;
    if (edge_flag(ei)){
      int4 sa = *(const int4*)&ei[8 * t];
      int4 sb = *(const int4*)&ei[8 * t + 4];
      int4 da = *(const int4*)&ei[2 * N_EDGES + 8 * t];
      int4 db = *(const int4*)&ei[2 * N_EDGES + 8 * t + 4];
      s0 = sa.x; s1 = sa.z; s2 = sb.x; s3 = sb.z;
      d0 = da.x; d1 = da.z; d2 = db.x; d3 = db.z;
    } else {
      int4 sa = *(const int4*)&ei[4 * t];
      int4 da = *(const int4*)&ei[N_EDGES + 4 * t];
      s0 = sa.x; s1 = sa.y; s2 = sa.z; s3 = sa.w;
      d0 = da.x; d1 = da.y; d2 = da.z; d3 = da.w;
    }
    col[atomicAdd(&fill[d0], 1)] = s0;
    col[atomicAdd(&fill[d1], 1)] = s1;
    col[atomicAdd(&fill[d2], 1)] = s2;
    col[atomicAdd(&fill[d3], 1)] = s3;
  } else {
    int n = t - N_EDGES / 4;
    if (n < N_NODES) col[atomicAdd(&fill[n], 1)] = n;   // self loop
  }
}

// layer 2: feat[N,64] @ W[64,256] -> h[N,256] (fp16); e_src/e_dst[N,4]
// Two-stage K over a 32 KiB LDS tile. Inner loop kept at unroll 4: full
// unroll spilled to scratch in R9 (VGPR 256, 1.2 GB spill writes, 35x slower).
__global__ __launch_bounds__(256) void k_transform2(
    const float* __restrict__ xin, const float* __restrict__ W,
    const float* __restrict__ aS, const float* __restrict__ aD,
    __half* __restrict__ h, float* __restrict__ es, float* __restrict__ ed){
  __shared__ float wl[32 * 256];   // 32 KiB
  int tid = threadIdx.x;
  int lane = tid & 63, wv = tid >> 6, head = lane >> 4;
  float4 s4 = *(const float4*)&aS[4 * lane];
  float4 d4 = *(const float4*)&aD[4 * lane];
  int base = (blockIdx.x * 4 + wv) * 8;   // 8 nodes per wave
  float xr[8];
  #pragma unroll
  for (int m = 0; m < 8; m++){
    int n = base + m;
    xr[m] = (n < N_NODES) ? xin[(size_t)n * 64 + lane] : 0.f;
  }
  float4 acc[8];
  #pragma unroll
  for (int m = 0; m < 8; m++) acc[m] = make_float4(0.f, 0.f, 0.f, 0.f);
  for (int hf = 0; hf < 2; hf++){
    if (hf) __syncthreads();   // all reads of previous half done
    const float4* Wv = (const float4*)(W + hf * 32 * 256);
    float4* wlv = (float4*)wl;
    #pragma unroll
    for (int i = 0; i < 8; i++) wlv[tid + 256 * i] = Wv[tid + 256 * i];
    __syncthreads();
    #pragma unroll 4
    for (int k = 0; k < 32; k++){
      float4 w4 = *(const float4*)&wl[k * 256 + 4 * lane];
      #pragma unroll
      for (int m = 0; m < 8; m++){
        float xv = __shfl(xr[m], hf * 32 + k);
        acc[m].x = fmaf(xv, w4.x, acc[m].x);
        acc[m].y = fmaf(xv, w4.y, acc[m].y);
        acc[m].z = fmaf(xv, w4.z, acc[m].z);
        acc[m].w = fmaf(xv, w4.w, acc[m].w);
      }
    }
  }
  #pragma unroll
  for (int m = 0; m < 8; m++){
    int n = base + m;
    if (n >= N_NODES) break;
    __half2 p0 = __floats2half2_rn(acc[m].x, acc[m].y);
    __half2 p1 = __floats2half2_rn(acc[m].z, acc[m].w);
    uint2 u; u.x = *(unsigned int*)&p0; u.y = *(unsigned int*)&p1;
    *(uint2*)&h[(size_t)n * 256 + 4 * lane] = u;
    float ps = acc[m].x*s4.x + acc[m].y*s4.y + acc[m].z*s4.z + acc[m].w*s4.w;
    float pd = acc[m].x*d4.x + acc[m].y*d4.y + acc[m].z*d4.z + acc[m].w*d4.w;
    #pragma unroll
    for (int off = 1; off < 16; off <<= 1){ ps += __shfl_xor(ps, off); pd += __shfl_xor(pd, off); }
    if ((lane & 15) == 0){ es[n * 4 + head] = ps; ed[n * 4 + head] = pd; }
  }
}

// layer 3: feat[N,64] @ W3[64,1] -> pk[N]={es3,h3}, ed3[N]. 4 nodes/wave,
// 16 lanes/node, float4 dot (was 64 lanes/node + 6-level reduce).
__global__ __launch_bounds__(256) void k_transform3(
    const float* __restrict__ xin, const float* __restrict__ W3,
    const float* __restrict__ aS, const float* __restrict__ aD,
    float2* __restrict__ pk, float* __restrict__ ed3){
  int gid = blockIdx.x * blockDim.x + threadIdx.x;
  int wv = gid >> 6, lane = gid & 63;
  int sub = lane >> 4, li = lane & 15;
  int d = wv * 4 + sub;
  if (d >= N_NODES) return;
  float4 xv = *(const float4*)&xin[(size_t)d * 64 + li * 4];
  float4 w4 = *(const float4*)&W3[li * 4];
  float v = xv.x*w4.x + xv.y*w4.y + xv.z*w4.z + xv.w*w4.w;
  #pragma unroll
  for (int off = 1; off < 16; off <<= 1) v += __shfl_xor(v, off);
  if (li == 0){
    pk[d] = make_float2(v * aS[0], v);   // (es3, h3): one 8B gather in agg3
    ed3[d] = v * aD[0];
  }
}

// ---------------- aggregation (layers 1,2): one wave per dst node ----------------
// No-max softmax (logits O(1-5) analytically; shift-invariant => identical math).
// 4-way unroll is the measured sweet spot: R7/R12 (4x, 24 VGPR, ~70% occ) = 68 us;
// R11 (8x, 36 VGPR, 58% occ) = 71.4 us; R6 (serialized) = 81.7 us.
static __device__ __forceinline__ void agg_step(float4& acc, uint2 u, float wt){
  float2 aa = __half22float2(*(__half2*)&u.x);
  float2 bb = __half22float2(*(__half2*)&u.y);
  acc.x = fmaf(wt, aa.x, acc.x); acc.y = fmaf(wt, aa.y, acc.y);
  acc.z = fmaf(wt, bb.x, acc.z); acc.w = fmaf(wt, bb.y, acc.w);
}

__global__ __launch_bounds__(256) void k_agg(
    const __half* __restrict__ h, const float* __restrict__ es, const float* __restrict__ ed,
    const int* __restrict__ rowptr, const int* __restrict__ col,
    const float* __restrict__ bias, float* __restrict__ outf){
  int gid = blockIdx.x * blockDim.x + threadIdx.x;
  int d = gid >> 6, lane = gid & 63;
  if (d >= N_NODES) return;
  int start = rowptr[d], end = rowptr[d + 1];
  int head = lane >> 4;
  float eh = ed[d * 4 + head];
  const __half* hp = h + 4 * lane;
  float4 acc = make_float4(0.f, 0.f, 0.f, 0.f);
  float wsum = 0.f;
  int i = start;
  for (; i + 4 <= end; i += 4){
    int s0 = col[i], s1 = col[i + 1], s2 = col[i + 2], s3 = col[i + 3];
    uint2 u0 = *(const uint2*)(hp + (size_t)s0 * 256);
    uint2 u1 = *(const uint2*)(hp + (size_t)s1 * 256);
    uint2 u2 = *(const uint2*)(hp + (size_t)s2 * 256);
    uint2 u3 = *(const uint2*)(hp + (size_t)s3 * 256);
    float e0 = es[s0 * 4 + head], e1 = es[s1 * 4 + head];
    float e2 = es[s2 * 4 + head], e3 = es[s3 * 4 + head];
    float w0 = __expf(lrelu(e0 + eh));
    float w1 = __expf(lrelu(e1 + eh));
    float w2 = __expf(lrelu(e2 + eh));
    float w3 = __expf(lrelu(e3 + eh));
    wsum += (w0 + w1) + (w2 + w3);
    agg_step(acc, u0, w0); agg_step(acc, u1, w1);
    agg_step(acc, u2, w2); agg_step(acc, u3, w3);
  }
  for (; i < end; i++){
    int s0 = col[i];
    uint2 u0 = *(const uint2*)(hp + (size_t)s0 * 256);
    float w0 = __expf(lrelu(es[s0 * 4 + head] + eh));
    wsum += w0;
    agg_step(acc, u0, w0);
  }
  float inv = 1.0f / (wsum + 1e-16f);
  acc.x *= inv; acc.y *= inv; acc.z *= inv; acc.w *= inv;
  #pragma unroll
  for (int off = 16; off < 64; off <<= 1){
    acc.x += __shfl_xor(acc.x, off);
    acc.y += __shfl_xor(acc.y, off);
    acc.z += __shfl_xor(acc.z, off);
    acc.w += __shfl_xor(acc.w, off);
  }
  if (lane < 16){
    float4 b4 = *(const float4*)&bias[4 * lane];
    float ox = 0.25f * acc.x + b4.x;
    float oy = 0.25f * acc.y + b4.y;
    float oz = 0.25f * acc.z + b4.z;
    float ow = 0.25f * acc.w + b4.w;
    ox = ox > 0.f ? ox : expm1f(ox);   // ELU
    oy = oy > 0.f ? oy : expm1f(oy);
    oz = oz > 0.f ? oz : expm1f(oz);
    ow = ow > 0.f ? ow : expm1f(ow);
    float4 o = make_float4(ox, oy, oz, ow);
    *(float4*)&outf[(size_t)d * 64 + 4 * lane] = o;
  }
}

// ---------------- aggregation layer 3 (1 head, 1 channel) + sigmoid ----------------
__global__ __launch_bounds__(256) void k_agg3(
    const float2* __restrict__ pk, const float* __restrict__ ed3,
    const int* __restrict__ rowptr, const int* __restrict__ col,
    const float* __restrict__ b3, float* __restrict__ out){
  int gid = blockIdx.x * blockDim.x + threadIdx.x;
  int wv = gid >> 6, lane = gid & 63;
  int sub = lane >> 4, li = lane & 15;
  int d = wv * 4 + sub;
  if (d < N_NODES){
    int start = rowptr[d], end = rowptr[d + 1];
    float edv = ed3[d];
    float num = 0.f, den = 0.f;
    for (int i = start + li; i < end; i += 16){
      float2 p = pk[col[i]];
      float wgt = __expf(lrelu(p.x + edv));   // no-max softmax
      den += wgt;
      num = fmaf(wgt, p.y, num);
    }
    #pragma unroll
    for (int off = 1; off < 16; off <<= 1){
      num += __shfl_xor(num, off);
      den += __shfl_xor(den, off);
    }
    if (li == 0){
      float v = num / (den + 1e-16f) + b3[0];
      out[d] = 1.f / (1.f + __expf(-v));
    }
  }
}

// ---------------- launcher: 8 kernels + 1 memset (was 11 kernels) ------------
extern "C" void kernel_launch(void* const* d_in, const int* in_sizes, int n_in,
                              void* d_out, int out_size, void* d_ws, size_t ws_size,
                              hipStream_t stream) {
  const float* x   = (const float*)d_in[0];
  const int*   ei  = (const int*)  d_in[1];
  const float* W1  = (const float*)d_in[2];
  const float* b1  = (const float*)d_in[3];
  const float* as1 = (const float*)d_in[4];
  const float* ad1 = (const float*)d_in[5];
  const float* W2  = (const float*)d_in[6];
  const float* b2  = (const float*)d_in[7];
  const float* as2 = (const float*)d_in[8];
  const float* ad2 = (const float*)d_in[9];
  const float* W3  = (const float*)d_in[10];
  const float* b3  = (const float*)d_in[11];
  const float* as3 = (const float*)d_in[12];
  const float* ad3 = (const float*)d_in[13];
  float* out = (float*)d_out;

  // workspace layout (256B-aligned); deg and done contiguous for one memset
  char* w = (char*)d_ws;
  size_t off = 0;
  auto alloc = [&](size_t bytes) -> char* {
    char* p = w + off;
    off += (bytes + 255) & ~size_t(255);
    return p;
  };
  int*    deg    = (int*)   alloc(N_NODES * 4);   // 200192 B rounded
  int*    done   = (int*)   alloc(256);           // scan barrier counter
  int*    fill   = (int*)   alloc(N_NODES * 4);
  int*    rowptr = (int*)   alloc((N_NODES + 1) * 4);
  int*    bsum   = (int*)   alloc(64 * 4);
  int*    col    = (int*)   alloc((size_t)N_TOT * 4);
  __half* h      = (__half*)alloc((size_t)N_NODES * 256 * 2);  // 25.6 MB fp16
  float*  es     = (float*) alloc((size_t)N_NODES * 4 * 4);
  float*  ed     = (float*) alloc((size_t)N_NODES * 4 * 4);
  float*  feat1  = (float*) alloc((size_t)N_NODES * 64 * 4);
  float*  feat2  = (float*) alloc((size_t)N_NODES * 64 * 4);
  float2* pk     = (float2*)alloc((size_t)N_NODES * 8);
  float*  ed3    = (float*) alloc(N_NODES * 4);
  (void)ws_size; (void)in_sizes; (void)n_in; (void)out_size;

  const size_t degsz = (((size_t)N_NODES * 4 + 255) & ~size_t(255)) + 256; // deg + done
  hipMemsetAsync(deg, 0, degsz, stream);

  const int grid_kA  = NB_COUNT + (N_NODES + 31) / 32;          // count ∥ transform1
  const int grid_sct = (N_EDGES / 4 + N_NODES + 255) / 256;
  const int grid_t2  = (N_NODES + 31) / 32;
  const int grid_wpn = (N_NODES * 64 + 255) / 256;              // wave per node
  const int grid_w4n = ((N_NODES + 3) / 4 * 64 + 255) / 256;    // 4 nodes per wave

  kA       <<<grid_kA, 256, 0, stream>>>(ei, deg, x, W1, as1, ad1, h, es, ed);
  k_scan   <<<NB_SCAN, 256, 0, stream>>>(deg, rowptr, fill, bsum, done);
  k_scatter<<<grid_sct, 256, 0, stream>>>(ei, fill, col);
  k_agg    <<<grid_wpn, 256, 0, stream>>>(h, es, ed, rowptr, col, b1, feat1);
  k_transform2<<<grid_t2, 256, 0, stream>>>(feat1, W2, as2, ad2, h, es, ed);
  k_agg    <<<grid_wpn, 256, 0, stream>>>(h, es, ed, rowptr, col, b2, feat2);
  k_transform3<<<grid_w4n, 256, 0, stream>>>(feat2, W3, as3, ad3, pk, ed3);
  k_agg3   <<<grid_w4n, 256, 0, stream>>>(pk, ed3, rowptr, col, b3, out);
}

// Round 15
// 379.648 us; speedup vs baseline: 3.3224x; 1.0141x over previous
//
#include <hip/hip_runtime.h>
#include <hip/hip_fp16.h>
#include <math.h>

// Problem constants (from reference)
#define N_NODES 50000
#define N_EDGES 800000
#define N_TOT   (N_EDGES + N_NODES)  // 850000 edges incl. self loops
#define NEG_SLOPE 0.2f
#define NB_COUNT 782   // ceil((N_EDGES/4)/256)
#define NB_SCAN  49    // ceil(N_NODES/1024)

static __device__ __forceinline__ float lrelu(float x){ return x >= 0.f ? x : NEG_SLOPE * x; }

// int64 vs int32 edge layout: odd 32-bit words all-zero => int64 (values < 50000).
static __device__ __forceinline__ int edge_flag(const int* __restrict__ ei){
  int o = 0;
  #pragma unroll
  for (int j = 1; j < 16; j += 2) o |= ei[j];
  return (o == 0) ? 1 : 0;
}

// ---------------- kA: k_count (blocks [0,NB_COUNT)) ∥ k_transform1 (rest) ----
__global__ __launch_bounds__(256) void kA(
    const int* __restrict__ ei, int* __restrict__ deg,
    const float* __restrict__ xin, const float* __restrict__ W,
    const float* __restrict__ aS, const float* __restrict__ aD,
    __half* __restrict__ h, float* __restrict__ es, float* __restrict__ ed){
  __shared__ float wl[8 * 256];
  if ((int)blockIdx.x < NB_COUNT){
    int t = blockIdx.x * 256 + threadIdx.x;
    if (t < N_EDGES / 4){
      int d0, d1, d2, d3;
      if (edge_flag(ei)){
        int4 a = *(const int4*)&ei[2 * N_EDGES + 8 * t];
        int4 b = *(const int4*)&ei[2 * N_EDGES + 8 * t + 4];
        d0 = a.x; d1 = a.z; d2 = b.x; d3 = b.z;
      } else {
        int4 a = *(const int4*)&ei[N_EDGES + 4 * t];
        d0 = a.x; d1 = a.y; d2 = a.z; d3 = a.w;
      }
      atomicAdd(&deg[d0], 1); atomicAdd(&deg[d1], 1);
      atomicAdd(&deg[d2], 1); atomicAdd(&deg[d3], 1);
    }
    return;
  }
  // ---- transform1: x[N,8] @ W[8,256] -> h fp16, es/ed f32 ----
  int bid = blockIdx.x - NB_COUNT;
  int tid = threadIdx.x;
  for (int i = tid; i < 8 * 256; i += 256) wl[i] = W[i];
  int lane = tid & 63, wv = tid >> 6, head = lane >> 4;
  float4 s4 = *(const float4*)&aS[4 * lane];
  float4 d4 = *(const float4*)&aD[4 * lane];
  __syncthreads();
  int base = (bid * 4 + wv) * 8;   // 8 nodes per wave
  for (int m = 0; m < 8; m++){
    int n = base + m;
    if (n >= N_NODES) break;
    float4 xa = *(const float4*)&xin[n * 8];
    float4 xb = *(const float4*)&xin[n * 8 + 4];
    float4 acc = make_float4(0.f, 0.f, 0.f, 0.f);
    #define T1STEP(k, xv) { float4 w4 = *(const float4*)&wl[(k)*256 + 4*lane]; \
      acc.x = fmaf(xv, w4.x, acc.x); acc.y = fmaf(xv, w4.y, acc.y); \
      acc.z = fmaf(xv, w4.z, acc.z); acc.w = fmaf(xv, w4.w, acc.w); }
    T1STEP(0, xa.x) T1STEP(1, xa.y) T1STEP(2, xa.z) T1STEP(3, xa.w)
    T1STEP(4, xb.x) T1STEP(5, xb.y) T1STEP(6, xb.z) T1STEP(7, xb.w)
    #undef T1STEP
    __half2 p0 = __floats2half2_rn(acc.x, acc.y);
    __half2 p1 = __floats2half2_rn(acc.z, acc.w);
    uint2 u; u.x = *(unsigned int*)&p0; u.y = *(unsigned int*)&p1;
    *(uint2*)&h[(size_t)n * 256 + 4 * lane] = u;
    float ps = acc.x*s4.x + acc.y*s4.y + acc.z*s4.z + acc.w*s4.w;
    float pd = acc.x*d4.x + acc.y*d4.y + acc.z*d4.z + acc.w*d4.w;
    #pragma unroll
    for (int off = 1; off < 16; off <<= 1){ ps += __shfl_xor(ps, off); pd += __shfl_xor(pd, off); }
    if ((lane & 15) == 0){ es[n * 4 + head] = ps; ed[n * 4 + head] = pd; }
  }
}

// ---------------- fused scan (was scan1+scan2+scan3) ----------------
// 49 blocks co-resident by construction => device-scope spin barrier safe.
__global__ __launch_bounds__(256) void k_scan(
    const int* __restrict__ deg, int* __restrict__ rowptr, int* __restrict__ fill,
    int* __restrict__ bsum, int* __restrict__ done){
  __shared__ int sd[256];
  __shared__ int s_off;
  int b = blockIdx.x, t = threadIdx.x;
  int base = b * 1024 + t * 4;
  int v0 = (base + 0 < N_NODES) ? deg[base + 0] + 1 : 0;
  int v1 = (base + 1 < N_NODES) ? deg[base + 1] + 1 : 0;
  int v2 = (base + 2 < N_NODES) ? deg[base + 2] + 1 : 0;
  int v3 = (base + 3 < N_NODES) ? deg[base + 3] + 1 : 0;
  int tsum = v0 + v1 + v2 + v3;
  sd[t] = tsum; __syncthreads();
  for (int off = 1; off < 256; off <<= 1){
    int vv = (t >= off) ? sd[t - off] : 0;
    __syncthreads();
    sd[t] += vv;
    __syncthreads();
  }
  int excl = sd[t] - tsum;
  if (t == 255){
    atomicExch(&bsum[b], sd[255]);   // publish chunk total
    __threadfence();
    atomicAdd(done, 1);
  }
  if (t == 0){
    while (atomicAdd(done, 0) < NB_SCAN) { }
  }
  __syncthreads();
  __threadfence();
  if (t < 64){                       // wave 0: off0 = sum of bsum[0..b)
    int u = (t < b) ? atomicAdd(&bsum[t], 0) : 0;
    #pragma unroll
    for (int off = 1; off < 64; off <<= 1) u += __shfl_xor(u, off);
    if (t == 0) s_off = u;
  }
  __syncthreads();
  int off0 = s_off;
  if (base + 0 < N_NODES){ int r = excl + off0;                rowptr[base+0] = r; fill[base+0] = r; }
  if (base + 1 < N_NODES){ int r = excl + v0 + off0;           rowptr[base+1] = r; fill[base+1] = r; }
  if (base + 2 < N_NODES){ int r = excl + v0 + v1 + off0;      rowptr[base+2] = r; fill[base+2] = r; }
  if (base + 3 < N_NODES){ int r = excl + v0 + v1 + v2 + off0; rowptr[base+3] = r; fill[base+3] = r; }
  if (b == 0 && t == 0) rowptr[N_NODES] = N_TOT;
}

// 4 edges per thread (int4 reads); tail threads place self loops.
__global__ void k_scatter(const int* __restrict__ ei,
                          int* __restrict__ fill, int* __restrict__ col){
  int t = blockIdx.x * blockDim.x + threadIdx.x;
  if (t < N_EDGES / 4){
    int s0, s1, s2, s3, d0, d1, d2, d3;
    if (edge_flag(ei)){
      int4 sa = *(const int4*)&ei[8 * t];
      int4 sb = *(const int4*)&ei[8 * t + 4];
      int4 da = *(const int4*)&ei[2 * N_EDGES + 8 * t];
      int4 db = *(const int4*)&ei[2 * N_EDGES + 8 * t + 4];
      s0 = sa.x; s1 = sa.z; s2 = sb.x; s3 = sb.z;
      d0 = da.x; d1 = da.z; d2 = db.x; d3 = db.z;
    } else {
      int4 sa = *(const int4*)&ei[4 * t];
      int4 da = *(const int4*)&ei[N_EDGES + 4 * t];
      s0 = sa.x; s1 = sa.y; s2 = sa.z; s3 = sa.w;
      d0 = da.x; d1 = da.y; d2 = da.z; d3 = da.w;
    }
    col[atomicAdd(&fill[d0], 1)] = s0;
    col[atomicAdd(&fill[d1], 1)] = s1;
    col[atomicAdd(&fill[d2], 1)] = s2;
    col[atomicAdd(&fill[d3], 1)] = s3;
  } else {
    int n = t - N_EDGES / 4;
    if (n < N_NODES) col[atomicAdd(&fill[n], 1)] = n;   // self loop
  }
}

// layer 2: feat[N,64] @ W[64,256] -> h[N,256] (fp16); e_src/e_dst[N,4]
// Two-stage K over a 32 KiB LDS tile; unroll 4 (full unroll spilled in R9).
__global__ __launch_bounds__(256) void k_transform2(
    const float* __restrict__ xin, const float* __restrict__ W,
    const float* __restrict__ aS, const float* __restrict__ aD,
    __half* __restrict__ h, float* __restrict__ es, float* __restrict__ ed){
  __shared__ float wl[32 * 256];   // 32 KiB
  int tid = threadIdx.x;
  int lane = tid & 63, wv = tid >> 6, head = lane >> 4;
  float4 s4 = *(const float4*)&aS[4 * lane];
  float4 d4 = *(const float4*)&aD[4 * lane];
  int base = (blockIdx.x * 4 + wv) * 8;   // 8 nodes per wave
  float xr[8];
  #pragma unroll
  for (int m = 0; m < 8; m++){
    int n = base + m;
    xr[m] = (n < N_NODES) ? xin[(size_t)n * 64 + lane] : 0.f;
  }
  float4 acc[8];
  #pragma unroll
  for (int m = 0; m < 8; m++) acc[m] = make_float4(0.f, 0.f, 0.f, 0.f);
  for (int hf = 0; hf < 2; hf++){
    if (hf) __syncthreads();
    const float4* Wv = (const float4*)(W + hf * 32 * 256);
    float4* wlv = (float4*)wl;
    #pragma unroll
    for (int i = 0; i < 8; i++) wlv[tid + 256 * i] = Wv[tid + 256 * i];
    __syncthreads();
    #pragma unroll 4
    for (int k = 0; k < 32; k++){
      float4 w4 = *(const float4*)&wl[k * 256 + 4 * lane];
      #pragma unroll
      for (int m = 0; m < 8; m++){
        float xv = __shfl(xr[m], hf * 32 + k);
        acc[m].x = fmaf(xv, w4.x, acc[m].x);
        acc[m].y = fmaf(xv, w4.y, acc[m].y);
        acc[m].z = fmaf(xv, w4.z, acc[m].z);
        acc[m].w = fmaf(xv, w4.w, acc[m].w);
      }
    }
  }
  #pragma unroll
  for (int m = 0; m < 8; m++){
    int n = base + m;
    if (n >= N_NODES) break;
    __half2 p0 = __floats2half2_rn(acc[m].x, acc[m].y);
    __half2 p1 = __floats2half2_rn(acc[m].z, acc[m].w);
    uint2 u; u.x = *(unsigned int*)&p0; u.y = *(unsigned int*)&p1;
    *(uint2*)&h[(size_t)n * 256 + 4 * lane] = u;
    float ps = acc[m].x*s4.x + acc[m].y*s4.y + acc[m].z*s4.z + acc[m].w*s4.w;
    float pd = acc[m].x*d4.x + acc[m].y*d4.y + acc[m].z*d4.z + acc[m].w*d4.w;
    #pragma unroll
    for (int off = 1; off < 16; off <<= 1){ ps += __shfl_xor(ps, off); pd += __shfl_xor(pd, off); }
    if ((lane & 15) == 0){ es[n * 4 + head] = ps; ed[n * 4 + head] = pd; }
  }
}

// ---------------- aggregation (layers 1,2): one wave per dst node ----------------
// No-max softmax (logits O(1-5); shift-invariant => identical math).
// 4-way unroll is the measured sweet spot (R7/R12: 68us; 8x: 71.4us; 2x: 76us).
// FUSE_T3=1 (layer 2): instead of writing feat2, compute layer 3's transform
// in-register — after the head-mean reduce every lane holds the channel-group
// (lane&15) value, so v = dot(ELU(acc)+b, W3) is a float4 dot + 4 shfl steps.
// Eliminates the k_transform3 dispatch and 25.6 MB of feat2 traffic.
static __device__ __forceinline__ void agg_step(float4& acc, uint2 u, float wt){
  float2 aa = __half22float2(*(__half2*)&u.x);
  float2 bb = __half22float2(*(__half2*)&u.y);
  acc.x = fmaf(wt, aa.x, acc.x); acc.y = fmaf(wt, aa.y, acc.y);
  acc.z = fmaf(wt, bb.x, acc.z); acc.w = fmaf(wt, bb.y, acc.w);
}

template<int FUSE_T3>
__global__ __launch_bounds__(256) void k_agg(
    const __half* __restrict__ h, const float* __restrict__ es, const float* __restrict__ ed,
    const int* __restrict__ rowptr, const int* __restrict__ col,
    const float* __restrict__ bias, float* __restrict__ outf,
    const float* __restrict__ W3, const float* __restrict__ aS3,
    const float* __restrict__ aD3, float2* __restrict__ pk, float* __restrict__ ed3){
  int gid = blockIdx.x * blockDim.x + threadIdx.x;
  int d = gid >> 6, lane = gid & 63;
  if (d >= N_NODES) return;
  int start = rowptr[d], end = rowptr[d + 1];
  int head = lane >> 4;
  float eh = ed[d * 4 + head];
  const __half* hp = h + 4 * lane;
  float4 acc = make_float4(0.f, 0.f, 0.f, 0.f);
  float wsum = 0.f;
  int i = start;
  for (; i + 4 <= end; i += 4){
    int s0 = col[i], s1 = col[i + 1], s2 = col[i + 2], s3 = col[i + 3];
    uint2 u0 = *(const uint2*)(hp + (size_t)s0 * 256);
    uint2 u1 = *(const uint2*)(hp + (size_t)s1 * 256);
    uint2 u2 = *(const uint2*)(hp + (size_t)s2 * 256);
    uint2 u3 = *(const uint2*)(hp + (size_t)s3 * 256);
    float e0 = es[s0 * 4 + head], e1 = es[s1 * 4 + head];
    float e2 = es[s2 * 4 + head], e3 = es[s3 * 4 + head];
    float w0 = __expf(lrelu(e0 + eh));
    float w1 = __expf(lrelu(e1 + eh));
    float w2 = __expf(lrelu(e2 + eh));
    float w3 = __expf(lrelu(e3 + eh));
    wsum += (w0 + w1) + (w2 + w3);
    agg_step(acc, u0, w0); agg_step(acc, u1, w1);
    agg_step(acc, u2, w2); agg_step(acc, u3, w3);
  }
  for (; i < end; i++){
    int s0 = col[i];
    uint2 u0 = *(const uint2*)(hp + (size_t)s0 * 256);
    float w0 = __expf(lrelu(es[s0 * 4 + head] + eh));
    wsum += w0;
    agg_step(acc, u0, w0);
  }
  float inv = 1.0f / (wsum + 1e-16f);
  acc.x *= inv; acc.y *= inv; acc.z *= inv; acc.w *= inv;
  // mean over heads: after this, EVERY lane holds the summed value for
  // channel group (lane & 15).
  #pragma unroll
  for (int off = 16; off < 64; off <<= 1){
    acc.x += __shfl_xor(acc.x, off);
    acc.y += __shfl_xor(acc.y, off);
    acc.z += __shfl_xor(acc.z, off);
    acc.w += __shfl_xor(acc.w, off);
  }
  int cg = lane & 15;
  float4 b4 = *(const float4*)&bias[4 * cg];
  float ox = 0.25f * acc.x + b4.x;
  float oy = 0.25f * acc.y + b4.y;
  float oz = 0.25f * acc.z + b4.z;
  float ow = 0.25f * acc.w + b4.w;
  ox = ox > 0.f ? ox : expm1f(ox);   // ELU
  oy = oy > 0.f ? oy : expm1f(oy);
  oz = oz > 0.f ? oz : expm1f(oz);
  ow = ow > 0.f ? ow : expm1f(ow);
  if (FUSE_T3){
    float4 w4 = *(const float4*)&W3[4 * cg];
    float v = ox*w4.x + oy*w4.y + oz*w4.z + ow*w4.w;
    #pragma unroll
    for (int off = 1; off < 16; off <<= 1) v += __shfl_xor(v, off);
    if (lane == 0){
      pk[d] = make_float2(v * aS3[0], v);   // (es3, h3)
      ed3[d] = v * aD3[0];
    }
  } else {
    if (lane < 16){
      float4 o = make_float4(ox, oy, oz, ow);
      *(float4*)&outf[(size_t)d * 64 + 4 * cg] = o;
    }
  }
}

// ---------------- aggregation layer 3 (1 head, 1 channel) + sigmoid ----------------
__global__ __launch_bounds__(256) void k_agg3(
    const float2* __restrict__ pk, const float* __restrict__ ed3,
    const int* __restrict__ rowptr, const int* __restrict__ col,
    const float* __restrict__ b3, float* __restrict__ out){
  int gid = blockIdx.x * blockDim.x + threadIdx.x;
  int wv = gid >> 6, lane = gid & 63;
  int sub = lane >> 4, li = lane & 15;
  int d = wv * 4 + sub;
  if (d < N_NODES){
    int start = rowptr[d], end = rowptr[d + 1];
    float edv = ed3[d];
    float num = 0.f, den = 0.f;
    for (int i = start + li; i < end; i += 16){
      float2 p = pk[col[i]];
      float wgt = __expf(lrelu(p.x + edv));   // no-max softmax
      den += wgt;
      num = fmaf(wgt, p.y, num);
    }
    #pragma unroll
    for (int off = 1; off < 16; off <<= 1){
      num += __shfl_xor(num, off);
      den += __shfl_xor(den, off);
    }
    if (li == 0){
      float v = num / (den + 1e-16f) + b3[0];
      out[d] = 1.f / (1.f + __expf(-v));
    }
  }
}

// ---------------- launcher: 7 kernels + 1 memset ------------
extern "C" void kernel_launch(void* const* d_in, const int* in_sizes, int n_in,
                              void* d_out, int out_size, void* d_ws, size_t ws_size,
                              hipStream_t stream) {
  const float* x   = (const float*)d_in[0];
  const int*   ei  = (const int*)  d_in[1];
  const float* W1  = (const float*)d_in[2];
  const float* b1  = (const float*)d_in[3];
  const float* as1 = (const float*)d_in[4];
  const float* ad1 = (const float*)d_in[5];
  const float* W2  = (const float*)d_in[6];
  const float* b2  = (const float*)d_in[7];
  const float* as2 = (const float*)d_in[8];
  const float* ad2 = (const float*)d_in[9];
  const float* W3  = (const float*)d_in[10];
  const float* b3  = (const float*)d_in[11];
  const float* as3 = (const float*)d_in[12];
  const float* ad3 = (const float*)d_in[13];
  float* out = (float*)d_out;

  // workspace layout (256B-aligned); deg and done contiguous for one memset
  char* w = (char*)d_ws;
  size_t off = 0;
  auto alloc = [&](size_t bytes) -> char* {
    char* p = w + off;
    off += (bytes + 255) & ~size_t(255);
    return p;
  };
  int*    deg    = (int*)   alloc(N_NODES * 4);
  int*    done   = (int*)   alloc(256);           // scan barrier counter
  int*    fill   = (int*)   alloc(N_NODES * 4);
  int*    rowptr = (int*)   alloc((N_NODES + 1) * 4);
  int*    bsum   = (int*)   alloc(64 * 4);
  int*    col    = (int*)   alloc((size_t)N_TOT * 4);
  __half* h      = (__half*)alloc((size_t)N_NODES * 256 * 2);  // 25.6 MB fp16
  float*  es     = (float*) alloc((size_t)N_NODES * 4 * 4);
  float*  ed     = (float*) alloc((size_t)N_NODES * 4 * 4);
  float*  feat1  = (float*) alloc((size_t)N_NODES * 64 * 4);
  float2* pk     = (float2*)alloc((size_t)N_NODES * 8);
  float*  ed3    = (float*) alloc(N_NODES * 4);
  (void)ws_size; (void)in_sizes; (void)n_in; (void)out_size;

  const size_t degsz = (((size_t)N_NODES * 4 + 255) & ~size_t(255)) + 256; // deg + done
  hipMemsetAsync(deg, 0, degsz, stream);

  const int grid_kA  = NB_COUNT + (N_NODES + 31) / 32;          // count ∥ transform1
  const int grid_sct = (N_EDGES / 4 + N_NODES + 255) / 256;
  const int grid_t2  = (N_NODES + 31) / 32;
  const int grid_wpn = (N_NODES * 64 + 255) / 256;              // wave per node
  const int grid_w4n = ((N_NODES + 3) / 4 * 64 + 255) / 256;    // 4 nodes per wave

  kA         <<<grid_kA, 256, 0, stream>>>(ei, deg, x, W1, as1, ad1, h, es, ed);
  k_scan     <<<NB_SCAN, 256, 0, stream>>>(deg, rowptr, fill, bsum, done);
  k_scatter  <<<grid_sct, 256, 0, stream>>>(ei, fill, col);
  k_agg<0>   <<<grid_wpn, 256, 0, stream>>>(h, es, ed, rowptr, col, b1, feat1,
                                            nullptr, nullptr, nullptr, nullptr, nullptr);
  k_transform2<<<grid_t2, 256, 0, stream>>>(feat1, W2, as2, ad2, h, es, ed);
  k_agg<1>   <<<grid_wpn, 256, 0, stream>>>(h, es, ed, rowptr, col, b2, nullptr,
                                            W3, as3, ad3, pk, ed3);
  k_agg3     <<<grid_w4n, 256, 0, stream>>>(pk, ed3, rowptr, col, b3, out);
}